// Round 1
// baseline (459.756 us; speedup 1.0000x reference)
//
#include <hip/hip_runtime.h>
#include <cstddef>

// ---------------------------------------------------------------------------
// EdgeSparkNet: two cross-attention blocks (head-mixing attention, per-token),
// metric-space pairwise distances -> sim = exp(clip(-dist)), per-position
// head-mixing attention over S=2500 with pos enc, mean-pool, LN.
// Round 1: straight fp32 pipeline. f64 only for the final mean/LN (cheap).
// ws footprint: ~88 MB (see offsets below).
// ---------------------------------------------------------------------------

namespace esn {

constexpr int kB   = 128;
constexpr int kN   = 50;
constexpr int kD   = 256;
constexpr int kR   = kB * kN;      // 6400 rows per feature set
constexpr int kR2  = 2 * kR;       // 12800
constexpr int kS   = kN * kN;      // 2500
constexpr int kFP  = 64;
constexpr int kChunks = 79;        // ceil(2500/32)

// ---------------- generic fp32 GEMM: C[M,N] = A[M,K] @ W[K,N] (+bias, relu) --
// tiles: 128x128 block, 8x8 per thread, BK=16. M%128==0, N%128==0, K%16==0.
template<bool RELU>
__global__ __launch_bounds__(256, 2)
void gemm_f32_kernel(const float* __restrict__ A, int lda,
                     const float* __restrict__ W, int ldw,
                     const float* __restrict__ bias,
                     float* __restrict__ C, int ldc, int K)
{
  __shared__ float sA[16][128];   // [k][m]
  __shared__ float sB[16][128];   // [k][n]
  const int tid = threadIdx.x;
  const int bm = blockIdx.x * 128;
  const int bn = blockIdx.y * 128;
  const int tn = tid & 15, tm = tid >> 4;
  const int m0 = tm * 8, n0 = tn * 8;
  float acc[8][8] = {};

  for (int kk = 0; kk < K; kk += 16) {
#pragma unroll
    for (int i = 0; i < 2; i++) {
      int slot = tid + i * 256;               // 0..511
      int m  = slot >> 2, k4 = (slot & 3) * 4;
      float4 a = *(const float4*)(A + (size_t)(bm + m) * lda + kk + k4);
      sA[k4 + 0][m] = a.x; sA[k4 + 1][m] = a.y;
      sA[k4 + 2][m] = a.z; sA[k4 + 3][m] = a.w;
      int kb = slot >> 5, n4 = (slot & 31) * 4;
      *(float4*)(&sB[kb][n4]) =
          *(const float4*)(W + (size_t)(kk + kb) * ldw + bn + n4);
    }
    __syncthreads();
#pragma unroll
    for (int k = 0; k < 16; k++) {
      float a[8], bv[8];
      *(float4*)(&a[0])  = *(const float4*)(&sA[k][m0]);
      *(float4*)(&a[4])  = *(const float4*)(&sA[k][m0 + 4]);
      *(float4*)(&bv[0]) = *(const float4*)(&sB[k][n0]);
      *(float4*)(&bv[4]) = *(const float4*)(&sB[k][n0 + 4]);
#pragma unroll
      for (int i = 0; i < 8; i++)
#pragma unroll
        for (int j = 0; j < 8; j++)
          acc[i][j] = fmaf(a[i], bv[j], acc[i][j]);
    }
    __syncthreads();
  }

  float bvals[8];
#pragma unroll
  for (int j = 0; j < 8; j++) bvals[j] = bias ? bias[bn + n0 + j] : 0.0f;
#pragma unroll
  for (int i = 0; i < 8; i++) {
    float o[8];
#pragma unroll
    for (int j = 0; j < 8; j++) {
      float v = acc[i][j] + bvals[j];
      if (RELU) v = fmaxf(v, 0.0f);
      o[j] = v;
    }
    float* cp = C + (size_t)(bm + m0 + i) * ldc + bn + n0;
    *(float4*)(cp)     = *(float4*)(&o[0]);
    *(float4*)(cp + 4) = *(float4*)(&o[4]);
  }
}

// ---------------- prep: concat Wqkv (256x768), bqkv(768), Msym ---------------
__global__ void prep_kernel(const float* __restrict__ wq, const float* __restrict__ wk,
                            const float* __restrict__ wv, const float* __restrict__ bq,
                            const float* __restrict__ bk, const float* __restrict__ bv,
                            const float* __restrict__ msm,
                            float* __restrict__ wqkv, float* __restrict__ bqkv,
                            float* __restrict__ msym)
{
  int tid = blockIdx.x * 256 + threadIdx.x;
  if (tid < 256 * 768) {
    int k = tid / 768, c = tid % 768;
    float v = (c < 256) ? wq[k * 256 + c]
            : (c < 512) ? wk[k * 256 + (c - 256)]
                        : wv[k * 256 + (c - 512)];
    wqkv[tid] = v;
  }
  if (tid < 768)
    bqkv[tid] = (tid < 256) ? bq[tid] : (tid < 512) ? bk[tid - 256] : bv[tid - 512];
  if (tid < 256 * 256) {
    int i = tid >> 8, j = tid & 255;
    msym[tid] = 0.5f * (msm[i * 256 + j] + msm[j * 256 + i]);
  }
}

// ---------------- cross-attention core (head-mixing, per token) --------------
// P rows: [r][0:256]=q, [256:512]=k, [512:768]=v of feature-row r.
// output row r uses q(r), k/v(partner(r)).  wave per row, 4 rows/block.
__global__ __launch_bounds__(256)
void ca_attn_kernel(const float* __restrict__ P, float* __restrict__ ATT)
{
  const int rib  = threadIdx.x >> 6;
  const int row  = blockIdx.x * 4 + rib;
  const int lane = threadIdx.x & 63;
  const int partner = (row < kR) ? row + kR : row - kR;
  const float* q = P + (size_t)row * 768;
  const float* k = P + (size_t)partner * 768 + 256;
  const float* v = P + (size_t)partner * 768 + 512;
  const int h = lane >> 3, g = lane & 7;

  float s = 0.0f;
#pragma unroll
  for (int i = 0; i < 8; i++) {
    float4 qa = *(const float4*)(q + h * 32 + i * 4);
    float4 ka = *(const float4*)(k + g * 32 + i * 4);
    s = fmaf(qa.x, ka.x, s); s = fmaf(qa.y, ka.y, s);
    s = fmaf(qa.z, ka.z, s); s = fmaf(qa.w, ka.w, s);
  }
  s *= 0.17677669529663687f;  // 1/sqrt(32)

  float mx = s;
#pragma unroll
  for (int d = 1; d < 8; d <<= 1) mx = fmaxf(mx, __shfl_xor(mx, d));
  float e = expf(s - mx);
  float se = e;
#pragma unroll
  for (int d = 1; d < 8; d <<= 1) se += __shfl_xor(se, d);
  float w = e / se;

  __shared__ float lds_w[4][64];
  lds_w[rib][lane] = w;
  __syncthreads();

  const int dc = lane & 7;
  float4 o = make_float4(0.f, 0.f, 0.f, 0.f);
#pragma unroll
  for (int gg = 0; gg < 8; gg++) {
    float wg = lds_w[rib][h * 8 + gg];
    float4 va = *(const float4*)(v + gg * 32 + dc * 4);
    o.x = fmaf(wg, va.x, o.x); o.y = fmaf(wg, va.y, o.y);
    o.z = fmaf(wg, va.z, o.z); o.w = fmaf(wg, va.w, o.w);
  }
  *(float4*)(ATT + (size_t)row * 256 + h * 32 + dc * 4) = o;
}

// ---------------- residual + LayerNorm over D=256 (wave per row) -------------
__global__ __launch_bounds__(256)
void ln_res_kernel(const float* __restrict__ Y, const float* __restrict__ R1,
                   const float* __restrict__ R2, const float* __restrict__ g,
                   const float* __restrict__ b, float* __restrict__ X)
{
  const int row  = blockIdx.x * 4 + (threadIdx.x >> 6);
  const int lane = threadIdx.x & 63;
  const float* res = (row < kR) ? (R1 + (size_t)row * 256)
                                : (R2 + (size_t)(row - kR) * 256);
  float4 y4 = *(const float4*)(Y + (size_t)row * 256 + lane * 4);
  float4 r4 = *(const float4*)(res + lane * 4);
  float v[4] = {y4.x + r4.x, y4.y + r4.y, y4.z + r4.z, y4.w + r4.w};

  float ssum = v[0] + v[1] + v[2] + v[3];
#pragma unroll
  for (int d = 1; d < 64; d <<= 1) ssum += __shfl_xor(ssum, d);
  float mu = ssum * (1.0f / 256.0f);
  float qq = 0.0f;
#pragma unroll
  for (int j = 0; j < 4; j++) { float dv = v[j] - mu; qq = fmaf(dv, dv, qq); }
#pragma unroll
  for (int d = 1; d < 64; d <<= 1) qq += __shfl_xor(qq, d);
  float rstd = rsqrtf(qq * (1.0f / 256.0f) + 1e-5f);

  float4 g4 = *(const float4*)(g + lane * 4);
  float4 b4 = *(const float4*)(b + lane * 4);
  float4 o;
  o.x = (v[0] - mu) * rstd * g4.x + b4.x;
  o.y = (v[1] - mu) * rstd * g4.y + b4.y;
  o.z = (v[2] - mu) * rstd * g4.z + b4.z;
  o.w = (v[3] - mu) * rstd * g4.w + b4.w;
  *(float4*)(X + (size_t)row * 256 + lane * 4) = o;
}

// ---------------- qdot: QD[r] = dot(TM[r], T[r]) ------------------------------
__global__ __launch_bounds__(256)
void qdot_kernel(const float* __restrict__ T, const float* __restrict__ TM,
                 float* __restrict__ QD)
{
  const int row  = blockIdx.x * 4 + (threadIdx.x >> 6);
  const int lane = threadIdx.x & 63;
  float4 a = *(const float4*)(T  + (size_t)row * 256 + lane * 4);
  float4 b = *(const float4*)(TM + (size_t)row * 256 + lane * 4);
  float s = a.x * b.x + a.y * b.y + a.z * b.z + a.w * b.w;
#pragma unroll
  for (int d = 1; d < 64; d <<= 1) s += __shfl_xor(s, d);
  if (lane == 0) QD[row] = s;
}

// ---------------- cross partials: CP[b][kh][n][m] over K-half ----------------
// per b: t1M (50x256) x t2 (50x256), padded to 64x64, split-K 2.
__global__ __launch_bounds__(256)
void cross_kernel(const float* __restrict__ T1M, const float* __restrict__ T2,
                  float* __restrict__ CP)
{
  const int b  = blockIdx.x >> 1;
  const int kh = blockIdx.x & 1;
  __shared__ float sA[128][64];  // [k][n]
  __shared__ float sB[128][64];  // [k][m]
  const int tid = threadIdx.x;
#pragma unroll
  for (int i = 0; i < 8; i++) {
    int slot = tid + i * 256;        // 0..2047
    int n  = slot >> 5;              // 0..63
    int k4 = (slot & 31) * 4;        // 0..124
    float4 a = make_float4(0.f, 0.f, 0.f, 0.f), c = a;
    if (n < 50) {
      a = *(const float4*)(T1M + ((size_t)b * 50 + n) * 256 + kh * 128 + k4);
      c = *(const float4*)(T2  + ((size_t)kR + b * 50 + n) * 256 + kh * 128 + k4);
    }
    sA[k4 + 0][n] = a.x; sA[k4 + 1][n] = a.y; sA[k4 + 2][n] = a.z; sA[k4 + 3][n] = a.w;
    sB[k4 + 0][n] = c.x; sB[k4 + 1][n] = c.y; sB[k4 + 2][n] = c.z; sB[k4 + 3][n] = c.w;
  }
  __syncthreads();
  const int tn = tid & 15, tm = tid >> 4;
  const int n0 = tn * 4, m0 = tm * 4;
  float acc[4][4] = {};
  for (int k = 0; k < 128; k++) {
    float4 a4 = *(const float4*)(&sA[k][n0]);
    float4 b4 = *(const float4*)(&sB[k][m0]);
    float a[4] = {a4.x, a4.y, a4.z, a4.w};
    float c[4] = {b4.x, b4.y, b4.z, b4.w};
#pragma unroll
    for (int i = 0; i < 4; i++)
#pragma unroll
      for (int j = 0; j < 4; j++)
        acc[i][j] = fmaf(a[i], c[j], acc[i][j]);
  }
#pragma unroll
  for (int i = 0; i < 4; i++) {
    float* cp = CP + (((size_t)b * 2 + kh) * 64 + n0 + i) * 64 + m0;
    *(float4*)cp = *(float4*)(&acc[i][0]);
  }
}

// ---------------- sim = exp(clip(-(q1+q2-2*cross), -10, 10)) -----------------
__global__ void sim_kernel(const float* __restrict__ CP, const float* __restrict__ QD,
                           float* __restrict__ SIM)
{
  int idx = blockIdx.x * 256 + threadIdx.x;
  if (idx >= kB * kS) return;
  int b = idx / kS, s = idx % kS;
  int n = s / kN, m = s % kN;
  float c = CP[(((size_t)b * 2 + 0) * 64 + n) * 64 + m]
          + CP[(((size_t)b * 2 + 1) * 64 + n) * 64 + m];
  float dist = QD[b * kN + n] + QD[kR + b * kN + m] - 2.0f * c;
  float z = -dist;  // TEMP = 1.0
  z = fminf(fmaxf(z, -10.0f), 10.0f);
  SIM[idx] = expf(z);
}

// ---------------- ap attention per (b,s): head-mixing over 8 heads of dim 8 --
// block = 32 positions x 8 heads; partial pooled sums -> PP[b][chunk][64]
__global__ __launch_bounds__(256)
void ap_kernel(const float* __restrict__ SIM, const float* __restrict__ pos,
               const float* __restrict__ wq, const float* __restrict__ bq,
               const float* __restrict__ wk, const float* __restrict__ bk,
               const float* __restrict__ wv, const float* __restrict__ bv,
               float* __restrict__ PP)
{
  const int b  = blockIdx.x / kChunks;
  const int ch = blockIdx.x % kChunks;
  const int sl = threadIdx.x >> 3;   // 0..31
  const int h  = threadIdx.x & 7;    // 0..7
  const int s  = ch * 32 + sl;
  const bool valid = (s < kS);

  __shared__ float sk[32][64];
  __shared__ float sv[32][64];
  __shared__ float satt[32][64];

  float f = valid ? SIM[(size_t)b * kS + s] : 0.0f;
  const float* pp = pos + (valid ? (size_t)s * 64 : 0) + h * 8;

  float qv[8];
#pragma unroll
  for (int d = 0; d < 8; d++) {
    int c = h * 8 + d;
    float pd = pp[d];
    qv[d] = fmaf(f, wq[c], bq[c] + pd);
    sk[sl][c] = fmaf(f, wk[c], bk[c] + pd);
    sv[sl][c] = fmaf(f, wv[c], bv[c]);
  }
  __syncthreads();

  float sc[8];
#pragma unroll
  for (int g = 0; g < 8; g++) {
    const float* kr = &sk[sl][g * 8];
    float a = 0.0f;
#pragma unroll
    for (int d = 0; d < 8; d++) a = fmaf(qv[d], kr[d], a);
    sc[g] = a * 0.35355339059327373f;  // 1/sqrt(8)
  }
  float mx = sc[0];
#pragma unroll
  for (int g = 1; g < 8; g++) mx = fmaxf(mx, sc[g]);
  float se = 0.0f;
#pragma unroll
  for (int g = 0; g < 8; g++) { sc[g] = expf(sc[g] - mx); se += sc[g]; }
  float inv = 1.0f / se;

  float av[8] = {};
#pragma unroll
  for (int g = 0; g < 8; g++) {
    float wg = sc[g] * inv;
    const float* vr = &sv[sl][g * 8];
#pragma unroll
    for (int d = 0; d < 8; d++) av[d] = fmaf(wg, vr[d], av[d]);
  }
  if (!valid) {
#pragma unroll
    for (int d = 0; d < 8; d++) av[d] = 0.0f;
  }
#pragma unroll
  for (int d = 0; d < 8; d++) satt[sl][h * 8 + d] = av[d];
  __syncthreads();

  for (int st = 16; st >= 1; st >>= 1) {
    if (sl < st) {
#pragma unroll
      for (int d = 0; d < 8; d++)
        satt[sl][h * 8 + d] += satt[sl + st][h * 8 + d];
    }
    __syncthreads();
  }
  if (sl == 0) {
#pragma unroll
    for (int d = 0; d < 8; d++)
      PP[((size_t)b * kChunks + ch) * 64 + h * 8 + d] = satt[0][h * 8 + d];
  }
}

// ---------------- final: pooled mean -> @wo+bo -> LN(64) -> out --------------
__global__ __launch_bounds__(64)
void final_kernel(const float* __restrict__ PP, const float* __restrict__ wo,
                  const float* __restrict__ bo, const float* __restrict__ lg,
                  const float* __restrict__ lb, float* __restrict__ out)
{
  const int b = blockIdx.x, j = threadIdx.x;
  double acc = 0.0;
  for (int c = 0; c < kChunks; c++)
    acc += (double)PP[((size_t)b * kChunks + c) * 64 + j];
  double pooled = acc / 2500.0;
  __shared__ double sp[64];
  sp[j] = pooled;
  __syncthreads();
  double o = (double)bo[j];
  for (int d = 0; d < 64; d++) o += sp[d] * (double)wo[d * 64 + j];
  double ssum = o;
#pragma unroll
  for (int d2 = 1; d2 < 64; d2 <<= 1) ssum += __shfl_xor(ssum, d2);
  double mu = ssum / 64.0;
  double dv = o - mu;
  double qq = dv * dv;
#pragma unroll
  for (int d2 = 1; d2 < 64; d2 <<= 1) qq += __shfl_xor(qq, d2);
  double var = qq / 64.0;
  double r = 1.0 / sqrt(var + 1e-5);
  out[(size_t)b * 64 + j] = (float)(dv * r * (double)lg[j] + (double)lb[j]);
}

}  // namespace esn

extern "C" void kernel_launch(void* const* d_in, const int* in_sizes, int n_in,
                              void* d_out, int out_size, void* d_ws, size_t ws_size,
                              hipStream_t stream)
{
  using namespace esn;
  const float* f1      = (const float*)d_in[0];
  const float* f2      = (const float*)d_in[1];
  const float* ca_wq   = (const float*)d_in[2];
  const float* ca_bq   = (const float*)d_in[3];
  const float* ca_wk   = (const float*)d_in[4];
  const float* ca_bk   = (const float*)d_in[5];
  const float* ca_wv   = (const float*)d_in[6];
  const float* ca_bv   = (const float*)d_in[7];
  const float* ca_wo   = (const float*)d_in[8];
  const float* ca_bo   = (const float*)d_in[9];
  const float* ln1_g   = (const float*)d_in[10];
  const float* ln1_b   = (const float*)d_in[11];
  const float* ln2_g   = (const float*)d_in[12];
  const float* ln2_b   = (const float*)d_in[13];
  const float* ca_w1   = (const float*)d_in[14];
  const float* ca_b1   = (const float*)d_in[15];
  const float* ca_w2   = (const float*)d_in[16];
  const float* ca_b2   = (const float*)d_in[17];
  const float* ms_met  = (const float*)d_in[18];
  const float* ms_wt   = (const float*)d_in[19];
  const float* ms_bt   = (const float*)d_in[20];
  const float* ap_wq   = (const float*)d_in[21];
  const float* ap_bq   = (const float*)d_in[22];
  const float* ap_wk   = (const float*)d_in[23];
  const float* ap_bk   = (const float*)d_in[24];
  const float* ap_wv   = (const float*)d_in[25];
  const float* ap_bv   = (const float*)d_in[26];
  const float* ap_pos  = (const float*)d_in[27];
  const float* ap_wo   = (const float*)d_in[28];
  const float* ap_bo   = (const float*)d_in[29];
  const float* ap_ln_g = (const float*)d_in[30];
  const float* ap_ln_b = (const float*)d_in[31];

  float* ws = (float*)d_ws;
  // region P (12800x768) is reused: H (12800x512) then T/TM (2x 12800x256)
  float* P    = ws;                    // [0,        9830400)
  float* H    = ws;                    // [0,        6553600)   after P dead
  float* Tt   = ws;                    // [0,        3276800)   after H dead
  float* TMb  = ws + 3276800;          // [3276800,  6553600)
  float* ATT  = ws + 9830400;          // [9830400, 13107200)  reused as E
  float* E    = ATT;
  float* X    = ws + 13107200;         // [13107200,16384000)
  float* Y    = ws + 16384000;         // [16384000,19660800)
  float* QD   = ws + 19660800;         // 12800
  float* WQKV = ws + 19673600;         // 196608
  float* BQKV = ws + 19870208;         // 768
  float* MSYM = ws + 19870976;         // 65536
  float* CP   = ws + 19936512;         // 1048576
  float* SIM  = ws + 20985088;         // 320000
  float* PP   = ws + 21305088;         // 647168  (end ~21.95M floats = 87.8MB)

  // 0) prep concat weights + symmetrized metric
  prep_kernel<<<768, 256, 0, stream>>>(ca_wq, ca_wk, ca_wv, ca_bq, ca_bk, ca_bv,
                                       ms_met, WQKV, BQKV, MSYM);
  // 1) QKV projections for both feature sets
  gemm_f32_kernel<false><<<dim3(50, 6), 256, 0, stream>>>(f1, 256, WQKV, 768, BQKV, P, 768, 256);
  gemm_f32_kernel<false><<<dim3(50, 6), 256, 0, stream>>>(f2, 256, WQKV, 768, BQKV, P + (size_t)kR * 768, 768, 256);
  // 2) head-mixing attention (both directions)
  ca_attn_kernel<<<kR2 / 4, 256, 0, stream>>>(P, ATT);
  // 3) o-proj, residual(features), LN1
  gemm_f32_kernel<false><<<dim3(100, 2), 256, 0, stream>>>(ATT, 256, ca_wo, 256, ca_bo, Y, 256, 256);
  ln_res_kernel<<<kR2 / 4, 256, 0, stream>>>(Y, f1, f2, ln1_g, ln1_b, X);
  // 4) FFN (relu) + residual + LN2
  gemm_f32_kernel<true ><<<dim3(100, 4), 256, 0, stream>>>(X, 256, ca_w1, 512, ca_b1, H, 512, 256);
  gemm_f32_kernel<false><<<dim3(100, 2), 256, 0, stream>>>(H, 512, ca_w2, 256, ca_b2, Y, 256, 512);
  ln_res_kernel<<<kR2 / 4, 256, 0, stream>>>(Y, X, X + (size_t)kR * 256, ln2_g, ln2_b, E);
  // 5) metric transform t, tM, row-dots
  gemm_f32_kernel<false><<<dim3(100, 2), 256, 0, stream>>>(E, 256, ms_wt, 256, ms_bt, Tt, 256, 256);
  gemm_f32_kernel<false><<<dim3(100, 2), 256, 0, stream>>>(Tt, 256, MSYM, 256, nullptr, TMb, 256, 256);
  qdot_kernel<<<kR2 / 4, 256, 0, stream>>>(Tt, TMb, QD);
  // 6) cross terms (split-K 2) + sim
  cross_kernel<<<kB * 2, 256, 0, stream>>>(TMb, Tt, CP);
  sim_kernel<<<(kB * kS + 255) / 256, 256, 0, stream>>>(CP, QD, SIM);
  // 7) ap attention partial pools
  ap_kernel<<<kB * kChunks, 256, 0, stream>>>(SIM, ap_pos, ap_wq, ap_bq, ap_wk, ap_bk,
                                              ap_wv, ap_bv, PP);
  // 8) pooled mean -> wo -> LN -> out
  final_kernel<<<kB, 64, 0, stream>>>(PP, ap_wo, ap_bo, ap_ln_g, ap_ln_b, (float*)d_out);
}

// Round 2
// 402.181 us; speedup vs baseline: 1.1432x; 1.1432x over previous
//
#include <hip/hip_runtime.h>
#include <cstddef>
#include <cstdint>

// ---------------------------------------------------------------------------
// EdgeSparkNet round 2: bf16x3 (split hi/lo bf16, 3 MFMAs) emulated-fp32 GEMMs
// on the matrix pipe; fp32 VALU for attention cores, LN, metric/sim/ap/final.
// ---------------------------------------------------------------------------

namespace esn {

constexpr int kB   = 128;
constexpr int kN   = 50;
constexpr int kR   = kB * kN;      // 6400 rows per set
constexpr int kR2  = 2 * kR;       // 12800
constexpr int kS   = kN * kN;      // 2500
constexpr int kChunks = 79;        // ceil(2500/32)

typedef __attribute__((ext_vector_type(8))) short short8;
typedef __attribute__((ext_vector_type(4))) float f32x4;

__device__ inline ushort f2bf_rn(float v) {
  uint32_t u = __float_as_uint(v);
  uint32_t r = (u + 0x7fffu + ((u >> 16) & 1u)) >> 16;  // round-nearest-even
  return (ushort)r;
}
__device__ inline float bf2f(ushort b) {
  return __uint_as_float(((uint32_t)b) << 16);
}
__device__ inline void split2(float v, ushort& h, ushort& l) {
  h = f2bf_rn(v);
  l = f2bf_rn(v - bf2f(h));
}

// ---------------- bf16x3 MFMA GEMM ------------------------------------------
// C[M,N] = A[M,K] @ W[K,N] (+bias, relu). A given as split bf16 [M][K] (h,l).
// B given as split bf16, PRE-TRANSPOSED: [N][K] (h,l).
// BM=BN=128, BK=32, 256 thr = 4 waves (2x2), wave = 64x64 = 4x4 frags 16x16.
// LDS tiles [rows][32] bf16, 16B slots XOR-swizzled: slot' = slot ^ ((row>>1)&3).
template<bool RELU, bool WF32, bool WSPLIT>
__global__ __launch_bounds__(256, 2)
void gemm_mfma_kernel(const ushort* __restrict__ Ah, const ushort* __restrict__ Al, int lda,
                      const ushort* __restrict__ Bh, const ushort* __restrict__ Bl, int ldb,
                      const float* __restrict__ bias,
                      float* __restrict__ C, int ldc,
                      ushort* __restrict__ Ch, ushort* __restrict__ Cl,
                      int K)
{
  __shared__ __align__(16) ushort sAh[128 * 32];
  __shared__ __align__(16) ushort sAl[128 * 32];
  __shared__ __align__(16) ushort sBh[128 * 32];
  __shared__ __align__(16) ushort sBl[128 * 32];

  const int tid  = threadIdx.x;
  const int lane = tid & 63;
  const int wave = tid >> 6;
  const int wm   = wave >> 1, wn = wave & 1;
  const int bm   = blockIdx.x * 128, bn = blockIdx.y * 128;

  f32x4 acc[4][4] = {};
  uint4 ld[8];

  // staging: 4 tiles x 512 slots(16B); thread covers 8 slots.
  auto issue = [&](int kk) {
#pragma unroll
    for (int i = 0; i < 8; i++) {
      int s = ((i & 1) << 8) + tid;       // slot in tile
      int row = s >> 2, sl = s & 3;
      const ushort* src;
      if ((i >> 1) == 0)      src = Ah + (size_t)(bm + row) * lda + kk + sl * 8;
      else if ((i >> 1) == 1) src = Al + (size_t)(bm + row) * lda + kk + sl * 8;
      else if ((i >> 1) == 2) src = Bh + (size_t)(bn + row) * ldb + kk + sl * 8;
      else                    src = Bl + (size_t)(bn + row) * ldb + kk + sl * 8;
      ld[i] = *(const uint4*)src;
    }
  };
  auto write_lds = [&]() {
#pragma unroll
    for (int i = 0; i < 8; i++) {
      int s = ((i & 1) << 8) + tid;
      int row = s >> 2, sl = s & 3;
      int slp = sl ^ ((row >> 1) & 3);
      ushort* dst = (i >> 1) == 0 ? sAh : (i >> 1) == 1 ? sAl
                  : (i >> 1) == 2 ? sBh : sBl;
      *(uint4*)(dst + row * 32 + slp * 8) = ld[i];
    }
  };

  issue(0);
  const int nK = K >> 5;
  for (int kt = 0; kt < nK; kt++) {
    __syncthreads();            // previous tile's frag reads done
    write_lds();
    __syncthreads();
    if (kt + 1 < nK) issue((kt + 1) << 5);

    const int r16 = lane & 15, kq = lane >> 4;
    short8 afh[4], afl[4], bfh[4], bfl[4];
#pragma unroll
    for (int f = 0; f < 4; f++) {
      int arow = wm * 64 + f * 16 + r16;
      int sa = kq ^ ((arow >> 1) & 3);
      afh[f] = *(const short8*)(sAh + arow * 32 + sa * 8);
      afl[f] = *(const short8*)(sAl + arow * 32 + sa * 8);
      int brow = wn * 64 + f * 16 + r16;
      int sb = kq ^ ((brow >> 1) & 3);
      bfh[f] = *(const short8*)(sBh + brow * 32 + sb * 8);
      bfl[f] = *(const short8*)(sBl + brow * 32 + sb * 8);
    }
#pragma unroll
    for (int mf = 0; mf < 4; mf++)
#pragma unroll
      for (int nf = 0; nf < 4; nf++) {
        acc[mf][nf] = __builtin_amdgcn_mfma_f32_16x16x32_bf16(afh[mf], bfh[nf], acc[mf][nf], 0, 0, 0);
        acc[mf][nf] = __builtin_amdgcn_mfma_f32_16x16x32_bf16(afh[mf], bfl[nf], acc[mf][nf], 0, 0, 0);
        acc[mf][nf] = __builtin_amdgcn_mfma_f32_16x16x32_bf16(afl[mf], bfh[nf], acc[mf][nf], 0, 0, 0);
      }
  }

  // epilogue: C/D frag layout col=lane&15, row=(lane>>4)*4+reg
  const int r16 = lane & 15, rq = lane >> 4;
#pragma unroll
  for (int nf = 0; nf < 4; nf++) {
    int col = bn + wn * 64 + nf * 16 + r16;
    float bv = bias ? bias[col] : 0.0f;
#pragma unroll
    for (int mf = 0; mf < 4; mf++) {
      int rowb = bm + wm * 64 + mf * 16 + rq * 4;
#pragma unroll
      for (int r = 0; r < 4; r++) {
        float v = acc[mf][nf][r] + bv;
        if (RELU) v = fmaxf(v, 0.0f);
        size_t off = (size_t)(rowb + r) * ldc + col;
        if (WF32) C[off] = v;
        if (WSPLIT) {
          ushort h, l; split2(v, h, l);
          Ch[off] = h; Cl[off] = l;
        }
      }
    }
  }
}

// ---------------- prep: split+transpose all weights, concat qkv bias ---------
__global__ void prep_w_kernel(const float* __restrict__ wq, const float* __restrict__ wk,
                              const float* __restrict__ wv, const float* __restrict__ bq,
                              const float* __restrict__ bk, const float* __restrict__ bv,
                              const float* __restrict__ wo, const float* __restrict__ w1,
                              const float* __restrict__ w2, const float* __restrict__ wt,
                              const float* __restrict__ msm,
                              ushort* __restrict__ qkvh, ushort* __restrict__ qkvl,
                              ushort* __restrict__ woh,  ushort* __restrict__ wol,
                              ushort* __restrict__ w1h,  ushort* __restrict__ w1l,
                              ushort* __restrict__ w2h,  ushort* __restrict__ w2l,
                              ushort* __restrict__ wth,  ushort* __restrict__ wtl,
                              ushort* __restrict__ msh,  ushort* __restrict__ msl,
                              float* __restrict__ bqkv)
{
  int idx = blockIdx.x * 256 + threadIdx.x;
  if (idx < 768)
    bqkv[idx] = idx < 256 ? bq[idx] : idx < 512 ? bk[idx - 256] : bv[idx - 512];
  float v; ushort *oh, *ol; int off;
  if (idx < 196608) {                       // WqkvT [768][256]
    int n = idx >> 8, k = idx & 255;
    v = n < 256 ? wq[k * 256 + n] : n < 512 ? wk[k * 256 + n - 256] : wv[k * 256 + n - 512];
    oh = qkvh; ol = qkvl; off = idx;
  } else if (idx < 262144) {                // woT [256][256]
    int i = idx - 196608; int n = i >> 8, k = i & 255;
    v = wo[k * 256 + n]; oh = woh; ol = wol; off = i;
  } else if (idx < 393216) {                // w1T [512][256]
    int i = idx - 262144; int n = i >> 8, k = i & 255;
    v = w1[k * 512 + n]; oh = w1h; ol = w1l; off = i;
  } else if (idx < 524288) {                // w2T [256][512]
    int i = idx - 393216; int n = i >> 9, k = i & 511;
    v = w2[k * 256 + n]; oh = w2h; ol = w2l; off = i;
  } else if (idx < 589824) {                // wtT [256][256]
    int i = idx - 524288; int n = i >> 8, k = i & 255;
    v = wt[k * 256 + n]; oh = wth; ol = wtl; off = i;
  } else if (idx < 655360) {                // msymT [256][256]
    int i = idx - 589824; int n = i >> 8, k = i & 255;
    v = 0.5f * (msm[k * 256 + n] + msm[n * 256 + k]); oh = msh; ol = msl; off = i;
  } else return;
  ushort h, l; split2(v, h, l);
  oh[off] = h; ol[off] = l;
}

// ---------------- split features fp32 -> (h,l) bf16 --------------------------
__global__ void split_f_kernel(const float* __restrict__ f1, const float* __restrict__ f2,
                               ushort* __restrict__ Fh, ushort* __restrict__ Fl)
{
  int idx = (blockIdx.x * 256 + threadIdx.x) * 4;   // 3,276,800 total elems
  const float* src = idx < kR * 256 ? f1 + idx : f2 + (idx - kR * 256);
  float4 v = *(const float4*)src;
  ushort h, l;
  split2(v.x, h, l); Fh[idx + 0] = h; Fl[idx + 0] = l;
  split2(v.y, h, l); Fh[idx + 1] = h; Fl[idx + 1] = l;
  split2(v.z, h, l); Fh[idx + 2] = h; Fl[idx + 2] = l;
  split2(v.w, h, l); Fh[idx + 3] = h; Fl[idx + 3] = l;
}

// ---------------- cross-attention core (fp32), writes split bf16 -------------
__global__ __launch_bounds__(256)
void ca_attn_kernel(const float* __restrict__ P, ushort* __restrict__ Ah,
                    ushort* __restrict__ Al)
{
  const int rib  = threadIdx.x >> 6;
  const int row  = blockIdx.x * 4 + rib;
  const int lane = threadIdx.x & 63;
  const int partner = (row < kR) ? row + kR : row - kR;
  const float* q = P + (size_t)row * 768;
  const float* k = P + (size_t)partner * 768 + 256;
  const float* v = P + (size_t)partner * 768 + 512;
  const int h = lane >> 3, g = lane & 7;

  float s = 0.0f;
#pragma unroll
  for (int i = 0; i < 8; i++) {
    float4 qa = *(const float4*)(q + h * 32 + i * 4);
    float4 ka = *(const float4*)(k + g * 32 + i * 4);
    s = fmaf(qa.x, ka.x, s); s = fmaf(qa.y, ka.y, s);
    s = fmaf(qa.z, ka.z, s); s = fmaf(qa.w, ka.w, s);
  }
  s *= 0.17677669529663687f;  // 1/sqrt(32)

  float mx = s;
#pragma unroll
  for (int d = 1; d < 8; d <<= 1) mx = fmaxf(mx, __shfl_xor(mx, d));
  float e = expf(s - mx);
  float se = e;
#pragma unroll
  for (int d = 1; d < 8; d <<= 1) se += __shfl_xor(se, d);
  float w = e / se;

  __shared__ float lds_w[4][64];
  lds_w[rib][lane] = w;
  __syncthreads();

  const int dc = lane & 7;
  float o[4] = {};
#pragma unroll
  for (int gg = 0; gg < 8; gg++) {
    float wg = lds_w[rib][h * 8 + gg];
    float4 va = *(const float4*)(v + gg * 32 + dc * 4);
    o[0] = fmaf(wg, va.x, o[0]); o[1] = fmaf(wg, va.y, o[1]);
    o[2] = fmaf(wg, va.z, o[2]); o[3] = fmaf(wg, va.w, o[3]);
  }
  size_t base = (size_t)row * 256 + h * 32 + dc * 4;
#pragma unroll
  for (int j = 0; j < 4; j++) {
    ushort hh, ll; split2(o[j], hh, ll);
    Ah[base + j] = hh; Al[base + j] = ll;
  }
}

// ---------------- residual + LayerNorm, writes optional fp32 + split ---------
template<bool WF32>
__global__ __launch_bounds__(256)
void ln_res_kernel(const float* __restrict__ Y, const float* __restrict__ R1,
                   const float* __restrict__ R2, const float* __restrict__ g,
                   const float* __restrict__ b, float* __restrict__ X,
                   ushort* __restrict__ Xh, ushort* __restrict__ Xl)
{
  const int row  = blockIdx.x * 4 + (threadIdx.x >> 6);
  const int lane = threadIdx.x & 63;
  const float* res = (row < kR) ? (R1 + (size_t)row * 256)
                                : (R2 + (size_t)(row - kR) * 256);
  float4 y4 = *(const float4*)(Y + (size_t)row * 256 + lane * 4);
  float4 r4 = *(const float4*)(res + lane * 4);
  float v[4] = {y4.x + r4.x, y4.y + r4.y, y4.z + r4.z, y4.w + r4.w};

  float ssum = v[0] + v[1] + v[2] + v[3];
#pragma unroll
  for (int d = 1; d < 64; d <<= 1) ssum += __shfl_xor(ssum, d);
  float mu = ssum * (1.0f / 256.0f);
  float qq = 0.0f;
#pragma unroll
  for (int j = 0; j < 4; j++) { float dv = v[j] - mu; qq = fmaf(dv, dv, qq); }
#pragma unroll
  for (int d = 1; d < 64; d <<= 1) qq += __shfl_xor(qq, d);
  float rstd = rsqrtf(qq * (1.0f / 256.0f) + 1e-5f);

  float4 g4 = *(const float4*)(g + lane * 4);
  float4 b4 = *(const float4*)(b + lane * 4);
  float o[4];
  o[0] = (v[0] - mu) * rstd * g4.x + b4.x;
  o[1] = (v[1] - mu) * rstd * g4.y + b4.y;
  o[2] = (v[2] - mu) * rstd * g4.z + b4.z;
  o[3] = (v[3] - mu) * rstd * g4.w + b4.w;
  size_t base = (size_t)row * 256 + lane * 4;
  if (WF32) *(float4*)(X + base) = *(float4*)o;
#pragma unroll
  for (int j = 0; j < 4; j++) {
    ushort hh, ll; split2(o[j], hh, ll);
    Xh[base + j] = hh; Xl[base + j] = ll;
  }
}

// ---------------- qdot --------------------------------------------------------
__global__ __launch_bounds__(256)
void qdot_kernel(const float* __restrict__ T, const float* __restrict__ TM,
                 float* __restrict__ QD)
{
  const int row  = blockIdx.x * 4 + (threadIdx.x >> 6);
  const int lane = threadIdx.x & 63;
  float4 a = *(const float4*)(T  + (size_t)row * 256 + lane * 4);
  float4 b = *(const float4*)(TM + (size_t)row * 256 + lane * 4);
  float s = a.x * b.x + a.y * b.y + a.z * b.z + a.w * b.w;
#pragma unroll
  for (int d = 1; d < 64; d <<= 1) s += __shfl_xor(s, d);
  if (lane == 0) QD[row] = s;
}

// ---------------- cross partials ---------------------------------------------
__global__ __launch_bounds__(256)
void cross_kernel(const float* __restrict__ T1M, const float* __restrict__ T2,
                  float* __restrict__ CP)
{
  const int b  = blockIdx.x >> 1;
  const int kh = blockIdx.x & 1;
  __shared__ float sA[128][64];
  __shared__ float sB[128][64];
  const int tid = threadIdx.x;
#pragma unroll
  for (int i = 0; i < 8; i++) {
    int slot = tid + i * 256;
    int n  = slot >> 5;
    int k4 = (slot & 31) * 4;
    float4 a = make_float4(0.f, 0.f, 0.f, 0.f), c = a;
    if (n < 50) {
      a = *(const float4*)(T1M + ((size_t)b * 50 + n) * 256 + kh * 128 + k4);
      c = *(const float4*)(T2  + ((size_t)kR + b * 50 + n) * 256 + kh * 128 + k4);
    }
    sA[k4 + 0][n] = a.x; sA[k4 + 1][n] = a.y; sA[k4 + 2][n] = a.z; sA[k4 + 3][n] = a.w;
    sB[k4 + 0][n] = c.x; sB[k4 + 1][n] = c.y; sB[k4 + 2][n] = c.z; sB[k4 + 3][n] = c.w;
  }
  __syncthreads();
  const int tn = tid & 15, tm = tid >> 4;
  const int n0 = tn * 4, m0 = tm * 4;
  float acc[4][4] = {};
  for (int k = 0; k < 128; k++) {
    float4 a4 = *(const float4*)(&sA[k][n0]);
    float4 b4 = *(const float4*)(&sB[k][m0]);
    float a[4] = {a4.x, a4.y, a4.z, a4.w};
    float c[4] = {b4.x, b4.y, b4.z, b4.w};
#pragma unroll
    for (int i = 0; i < 4; i++)
#pragma unroll
      for (int j = 0; j < 4; j++)
        acc[i][j] = fmaf(a[i], c[j], acc[i][j]);
  }
#pragma unroll
  for (int i = 0; i < 4; i++) {
    float* cp = CP + (((size_t)b * 2 + kh) * 64 + n0 + i) * 64 + m0;
    *(float4*)cp = *(float4*)(&acc[i][0]);
  }
}

// ---------------- sim ---------------------------------------------------------
__global__ void sim_kernel(const float* __restrict__ CP, const float* __restrict__ QD,
                           float* __restrict__ SIM)
{
  int idx = blockIdx.x * 256 + threadIdx.x;
  if (idx >= kB * kS) return;
  int b = idx / kS, s = idx % kS;
  int n = s / kN, m = s % kN;
  float c = CP[(((size_t)b * 2 + 0) * 64 + n) * 64 + m]
          + CP[(((size_t)b * 2 + 1) * 64 + n) * 64 + m];
  float dist = QD[b * kN + n] + QD[kR + b * kN + m] - 2.0f * c;
  float z = -dist;
  z = fminf(fmaxf(z, -10.0f), 10.0f);
  SIM[idx] = expf(z);
}

// ---------------- ap attention ------------------------------------------------
__global__ __launch_bounds__(256)
void ap_kernel(const float* __restrict__ SIM, const float* __restrict__ pos,
               const float* __restrict__ wq, const float* __restrict__ bq,
               const float* __restrict__ wk, const float* __restrict__ bk,
               const float* __restrict__ wv, const float* __restrict__ bv,
               float* __restrict__ PP)
{
  const int b  = blockIdx.x / kChunks;
  const int ch = blockIdx.x % kChunks;
  const int sl = threadIdx.x >> 3;
  const int h  = threadIdx.x & 7;
  const int s  = ch * 32 + sl;
  const bool valid = (s < kS);

  __shared__ float sk[32][64];
  __shared__ float sv[32][64];
  __shared__ float satt[32][64];

  float f = valid ? SIM[(size_t)b * kS + s] : 0.0f;
  const float* pp = pos + (valid ? (size_t)s * 64 : 0) + h * 8;

  float qv[8];
#pragma unroll
  for (int d = 0; d < 8; d++) {
    int c = h * 8 + d;
    float pd = pp[d];
    qv[d] = fmaf(f, wq[c], bq[c] + pd);
    sk[sl][c] = fmaf(f, wk[c], bk[c] + pd);
    sv[sl][c] = fmaf(f, wv[c], bv[c]);
  }
  __syncthreads();

  float sc[8];
#pragma unroll
  for (int g = 0; g < 8; g++) {
    const float* kr = &sk[sl][g * 8];
    float a = 0.0f;
#pragma unroll
    for (int d = 0; d < 8; d++) a = fmaf(qv[d], kr[d], a);
    sc[g] = a * 0.35355339059327373f;
  }
  float mx = sc[0];
#pragma unroll
  for (int g = 1; g < 8; g++) mx = fmaxf(mx, sc[g]);
  float se = 0.0f;
#pragma unroll
  for (int g = 0; g < 8; g++) { sc[g] = expf(sc[g] - mx); se += sc[g]; }
  float inv = 1.0f / se;

  float av[8] = {};
#pragma unroll
  for (int g = 0; g < 8; g++) {
    float wg = sc[g] * inv;
    const float* vr = &sv[sl][g * 8];
#pragma unroll
    for (int d = 0; d < 8; d++) av[d] = fmaf(wg, vr[d], av[d]);
  }
  if (!valid) {
#pragma unroll
    for (int d = 0; d < 8; d++) av[d] = 0.0f;
  }
#pragma unroll
  for (int d = 0; d < 8; d++) satt[sl][h * 8 + d] = av[d];
  __syncthreads();

  for (int st = 16; st >= 1; st >>= 1) {
    if (sl < st) {
#pragma unroll
      for (int d = 0; d < 8; d++)
        satt[sl][h * 8 + d] += satt[sl + st][h * 8 + d];
    }
    __syncthreads();
  }
  if (sl == 0) {
#pragma unroll
    for (int d = 0; d < 8; d++)
      PP[((size_t)b * kChunks + ch) * 64 + h * 8 + d] = satt[0][h * 8 + d];
  }
}

// ---------------- final -------------------------------------------------------
__global__ __launch_bounds__(64)
void final_kernel(const float* __restrict__ PP, const float* __restrict__ wo,
                  const float* __restrict__ bo, const float* __restrict__ lg,
                  const float* __restrict__ lb, float* __restrict__ out)
{
  const int b = blockIdx.x, j = threadIdx.x;
  double acc = 0.0;
  for (int c = 0; c < kChunks; c++)
    acc += (double)PP[((size_t)b * kChunks + c) * 64 + j];
  double pooled = acc / 2500.0;
  __shared__ double sp[64];
  sp[j] = pooled;
  __syncthreads();
  double o = (double)bo[j];
  for (int d = 0; d < 64; d++) o += sp[d] * (double)wo[d * 64 + j];
  double ssum = o;
#pragma unroll
  for (int d2 = 1; d2 < 64; d2 <<= 1) ssum += __shfl_xor(ssum, d2);
  double mu = ssum / 64.0;
  double dv = o - mu;
  double qq = dv * dv;
#pragma unroll
  for (int d2 = 1; d2 < 64; d2 <<= 1) qq += __shfl_xor(qq, d2);
  double var = qq / 64.0;
  double r = 1.0 / sqrt(var + 1e-5);
  out[(size_t)b * 64 + j] = (float)(dv * r * (double)lg[j] + (double)lb[j]);
}

}  // namespace esn

extern "C" void kernel_launch(void* const* d_in, const int* in_sizes, int n_in,
                              void* d_out, int out_size, void* d_ws, size_t ws_size,
                              hipStream_t stream)
{
  using namespace esn;
  const float* f1      = (const float*)d_in[0];
  const float* f2      = (const float*)d_in[1];
  const float* ca_wq   = (const float*)d_in[2];
  const float* ca_bq   = (const float*)d_in[3];
  const float* ca_wk   = (const float*)d_in[4];
  const float* ca_bk   = (const float*)d_in[5];
  const float* ca_wv   = (const float*)d_in[6];
  const float* ca_bv   = (const float*)d_in[7];
  const float* ca_wo   = (const float*)d_in[8];
  const float* ca_bo   = (const float*)d_in[9];
  const float* ln1_g   = (const float*)d_in[10];
  const float* ln1_b   = (const float*)d_in[11];
  const float* ln2_g   = (const float*)d_in[12];
  const float* ln2_b   = (const float*)d_in[13];
  const float* ca_w1   = (const float*)d_in[14];
  const float* ca_b1   = (const float*)d_in[15];
  const float* ca_w2   = (const float*)d_in[16];
  const float* ca_b2   = (const float*)d_in[17];
  const float* ms_met  = (const float*)d_in[18];
  const float* ms_wt   = (const float*)d_in[19];
  const float* ms_bt   = (const float*)d_in[20];
  const float* ap_wq   = (const float*)d_in[21];
  const float* ap_bq   = (const float*)d_in[22];
  const float* ap_wk   = (const float*)d_in[23];
  const float* ap_bk   = (const float*)d_in[24];
  const float* ap_wv   = (const float*)d_in[25];
  const float* ap_bv   = (const float*)d_in[26];
  const float* ap_pos  = (const float*)d_in[27];
  const float* ap_wo   = (const float*)d_in[28];
  const float* ap_bo   = (const float*)d_in[29];
  const float* ap_ln_g = (const float*)d_in[30];
  const float* ap_ln_b = (const float*)d_in[31];

  float* ws = (float*)d_ws;
  // fp32 regions (offsets in floats)
  float*  P    = ws;                         // [0, 9,830,400)   12800x768
  ushort* Hh   = (ushort*)(ws);              // [0, 3,276,800)   12800x512 bf16 (after P dead)
  ushort* Hl   = (ushort*)(ws + 3276800);    // [3,276,800, 6,553,600)
  float*  TM   = ws;                         // [0, 3,276,800)   (after H dead)
  ushort* Th   = (ushort*)(ws + 3276800);    // [3,276,800, 4,915,200)
  ushort* Tl   = (ushort*)(ws + 4915200);    // [4,915,200, 6,553,600)
  float*  Tt   = ws + 6553600;               // [6,553,600, 9,830,400)
  // split-pair region (F -> ATT -> Xsplit -> Esplit), 12800x256 bf16 each
  ushort* S1h  = (ushort*)(ws + 9830400);    // [9,830,400, 11,468,800)
  ushort* S1l  = (ushort*)(ws + 11468800);   // [11,468,800, 13,107,200)
  float*  X    = ws + 13107200;              // [13,107,200, 16,384,000)
  float*  Y    = ws + 16384000;              // [16,384,000, 19,660,800)
  float*  CP   = ws + 16384000;              // overlays Y (Y dead before cross)
  float*  SIM  = ws + 17432576;              // 320,000
  float*  PP   = ws + 17752576;              // 647,168 (ends 18,399,744)
  float*  QD   = ws + 19660800;              // 12,800
  // weights (split + transposed), bf16
  ushort* Wqh  = (ushort*)(ws + 19673600);   // 196,608 bf16 = 98,304 floats
  ushort* Wql  = (ushort*)(ws + 19771904);
  ushort* Woh  = (ushort*)(ws + 19870208);   // 65,536 bf16 = 32,768 floats
  ushort* Wol  = (ushort*)(ws + 19902976);
  ushort* W1h  = (ushort*)(ws + 19935744);   // 131,072 bf16 = 65,536 floats
  ushort* W1l  = (ushort*)(ws + 20001280);
  ushort* W2h  = (ushort*)(ws + 20066816);
  ushort* W2l  = (ushort*)(ws + 20132352);
  ushort* Wth  = (ushort*)(ws + 20197888);
  ushort* Wtl  = (ushort*)(ws + 20230656);
  ushort* Msh  = (ushort*)(ws + 20263424);
  ushort* Msl  = (ushort*)(ws + 20296192);
  float*  BQKV = ws + 20328960;              // 768 (ends 20,329,728 fl = 81.3 MB)

  // 0) prep weights + split features
  prep_w_kernel<<<2560, 256, 0, stream>>>(ca_wq, ca_wk, ca_wv, ca_bq, ca_bk, ca_bv,
                                          ca_wo, ca_w1, ca_w2, ms_wt, ms_met,
                                          Wqh, Wql, Woh, Wol, W1h, W1l, W2h, W2l,
                                          Wth, Wtl, Msh, Msl, BQKV);
  split_f_kernel<<<3200, 256, 0, stream>>>(f1, f2, S1h, S1l);
  // 1) QKV: P = F @ Wqkv + b   [12800x768]
  gemm_mfma_kernel<false, true, false><<<dim3(100, 6), 256, 0, stream>>>(
      S1h, S1l, 256, Wqh, Wql, 256, BQKV, P, 768, nullptr, nullptr, 256);
  // 2) head-mixing cross-attention -> ATT split (into S1)
  ca_attn_kernel<<<kR2 / 4, 256, 0, stream>>>(P, S1h, S1l);
  // 3) o-proj: Y = ATT @ wo + bo
  gemm_mfma_kernel<false, true, false><<<dim3(100, 2), 256, 0, stream>>>(
      S1h, S1l, 256, Woh, Wol, 256, ca_bo, Y, 256, nullptr, nullptr, 256);
  // 4) LN1 -> X fp32 + Xsplit (into S1)
  ln_res_kernel<true><<<kR2 / 4, 256, 0, stream>>>(Y, f1, f2, ln1_g, ln1_b, X, S1h, S1l);
  // 5) FFN1 (relu) -> H split
  gemm_mfma_kernel<true, false, true><<<dim3(100, 4), 256, 0, stream>>>(
      S1h, S1l, 256, W1h, W1l, 256, ca_b1, nullptr, 512, Hh, Hl, 256);
  // 6) FFN2 -> Y
  gemm_mfma_kernel<false, true, false><<<dim3(100, 2), 256, 0, stream>>>(
      Hh, Hl, 512, W2h, W2l, 512, ca_b2, Y, 256, nullptr, nullptr, 512);
  // 7) LN2 -> Esplit (into S1)
  ln_res_kernel<false><<<kR2 / 4, 256, 0, stream>>>(Y, X, X + (size_t)kR * 256,
                                                    ln2_g, ln2_b, nullptr, S1h, S1l);
  // 8) t = E @ wt + bt  (fp32 + split)
  gemm_mfma_kernel<false, true, true><<<dim3(100, 2), 256, 0, stream>>>(
      S1h, S1l, 256, Wth, Wtl, 256, ms_bt, Tt, 256, Th, Tl, 256);
  // 9) tM = t @ Msym  (fp32)
  gemm_mfma_kernel<false, true, false><<<dim3(100, 2), 256, 0, stream>>>(
      Th, Tl, 256, Msh, Msl, 256, nullptr, TM, 256, nullptr, nullptr, 256);
  // 10) qdot, cross, sim
  qdot_kernel<<<kR2 / 4, 256, 0, stream>>>(Tt, TM, QD);
  cross_kernel<<<kB * 2, 256, 0, stream>>>(TM, Tt, CP);
  sim_kernel<<<(kB * kS + 255) / 256, 256, 0, stream>>>(CP, QD, SIM);
  // 11) ap attention partial pools + final
  ap_kernel<<<kB * kChunks, 256, 0, stream>>>(SIM, ap_pos, ap_wq, ap_bq, ap_wk, ap_bk,
                                              ap_wv, ap_bv, PP);
  final_kernel<<<kB, 64, 0, stream>>>(PP, ap_wo, ap_bo, ap_ln_g, ap_ln_b, (float*)d_out);
}

// Round 3
// 259.010 us; speedup vs baseline: 1.7751x; 1.5528x over previous
//
#include <hip/hip_runtime.h>
#include <cstddef>
#include <cstdint>

// ---------------------------------------------------------------------------
// EdgeSparkNet round 3: bf16x3 MFMA GEMMs with global_load_lds staging
// (no register round-trip -> no scratch spill), pre-swizzled source addresses,
// swizzled ds_read_b128 fragment reads. Rest of pipeline unchanged.
// ---------------------------------------------------------------------------

namespace esn {

constexpr int kB   = 128;
constexpr int kN   = 50;
constexpr int kR   = kB * kN;      // 6400 rows per set
constexpr int kR2  = 2 * kR;       // 12800
constexpr int kS   = kN * kN;      // 2500
constexpr int kChunks = 79;        // ceil(2500/32)

typedef __attribute__((ext_vector_type(8))) short short8;
typedef __attribute__((ext_vector_type(4))) float f32x4;

__device__ inline ushort f2bf_rn(float v) {
  uint32_t u = __float_as_uint(v);
  uint32_t r = (u + 0x7fffu + ((u >> 16) & 1u)) >> 16;  // round-nearest-even
  return (ushort)r;
}
__device__ inline float bf2f(ushort b) {
  return __uint_as_float(((uint32_t)b) << 16);
}
__device__ inline void split2(float v, ushort& h, ushort& l) {
  h = f2bf_rn(v);
  l = f2bf_rn(v - bf2f(h));
}

// async global->LDS, 16B per lane; LDS dest = wave-uniform base + lane*16
__device__ __forceinline__ void gld16(const ushort* g, ushort* l) {
  __builtin_amdgcn_global_load_lds(
      (const __attribute__((address_space(1))) void*)g,
      (__attribute__((address_space(3))) void*)l,
      16, 0, 0);
}

// ---------------- bf16x3 MFMA GEMM ------------------------------------------
// C[M,N] = A[M,K] @ W[K,N] (+bias, relu). A: split bf16 [M][K] (h,l).
// B: split bf16 PRE-TRANSPOSED [N][K] (h,l).
// BM=BN=128, BK=32, 256 thr = 4 waves (2x2); wave tile 64x64 = 4x4 frags 16x16.
// LDS [row][4 slots of 8 ushort], slot XOR-swizzled by ((row>>1)&3).
// Contract: LDS[row][slot] holds global chunk (slot ^ swz(row)) — maintained
// on the write side by pre-swizzling the per-lane global source address.
template<bool RELU, bool WF32, bool WSPLIT>
__global__ __launch_bounds__(256)
void gemm_mfma_kernel(const ushort* __restrict__ Ah, const ushort* __restrict__ Al, int lda,
                      const ushort* __restrict__ Bh, const ushort* __restrict__ Bl, int ldb,
                      const float* __restrict__ bias,
                      float* __restrict__ C, int ldc,
                      ushort* __restrict__ Ch, ushort* __restrict__ Cl,
                      int K)
{
  __shared__ __align__(16) ushort sAh[128 * 32];
  __shared__ __align__(16) ushort sAl[128 * 32];
  __shared__ __align__(16) ushort sBh[128 * 32];
  __shared__ __align__(16) ushort sBl[128 * 32];

  const int tid  = threadIdx.x;
  const int lane = tid & 63;
  const int wave = tid >> 6;
  const int wm   = wave >> 1, wn = wave & 1;
  const int bm   = blockIdx.x * 128, bn = blockIdx.y * 128;

  const int lrow  = lane >> 2;   // 0..15 within a 16-row staging group
  const int lslot = lane & 3;

  f32x4 acc[4][4] = {};

  const int nK = K >> 5;
  for (int kt = 0; kt < nK; kt++) {
    const int kk = kt << 5;
    // ---- stage: 2 groups x 16 rows per wave, 4 buffers, 16B/lane ----
#pragma unroll
    for (int i = 0; i < 2; i++) {
      const int grp  = wave * 32 + i * 16;     // wave-uniform base row
      const int row  = grp + lrow;             // per-lane row
      const int c    = lslot ^ ((row >> 1) & 3);  // pre-swizzled source chunk
      const size_t aoff = (size_t)(bm + row) * lda + kk + c * 8;
      const size_t boff = (size_t)(bn + row) * ldb + kk + c * 8;
      gld16(Ah + aoff, sAh + grp * 32);
      gld16(Al + aoff, sAl + grp * 32);
      gld16(Bh + boff, sBh + grp * 32);
      gld16(Bl + boff, sBl + grp * 32);
    }
    __syncthreads();   // drains vmcnt (gload_lds) for all waves

    // ---- fragments (swizzled ds_read_b128) + MFMA ----
    const int r16 = lane & 15, kq = lane >> 4;
    short8 afh[4], afl[4], bfh[4], bfl[4];
#pragma unroll
    for (int f = 0; f < 4; f++) {
      int arow = wm * 64 + f * 16 + r16;
      int sa = kq ^ ((arow >> 1) & 3);
      afh[f] = *(const short8*)(sAh + arow * 32 + sa * 8);
      afl[f] = *(const short8*)(sAl + arow * 32 + sa * 8);
      int brow = wn * 64 + f * 16 + r16;
      int sb = kq ^ ((brow >> 1) & 3);
      bfh[f] = *(const short8*)(sBh + brow * 32 + sb * 8);
      bfl[f] = *(const short8*)(sBl + brow * 32 + sb * 8);
    }
#pragma unroll
    for (int mf = 0; mf < 4; mf++)
#pragma unroll
      for (int nf = 0; nf < 4; nf++) {
        acc[mf][nf] = __builtin_amdgcn_mfma_f32_16x16x32_bf16(afh[mf], bfh[nf], acc[mf][nf], 0, 0, 0);
        acc[mf][nf] = __builtin_amdgcn_mfma_f32_16x16x32_bf16(afh[mf], bfl[nf], acc[mf][nf], 0, 0, 0);
        acc[mf][nf] = __builtin_amdgcn_mfma_f32_16x16x32_bf16(afl[mf], bfh[nf], acc[mf][nf], 0, 0, 0);
      }
    __syncthreads();   // protect LDS from next tile's staging
  }

  // epilogue: C/D frag layout col=lane&15, row=(lane>>4)*4+reg
  const int r16 = lane & 15, rq = lane >> 4;
#pragma unroll
  for (int nf = 0; nf < 4; nf++) {
    int col = bn + wn * 64 + nf * 16 + r16;
    float bv = bias ? bias[col] : 0.0f;
#pragma unroll
    for (int mf = 0; mf < 4; mf++) {
      int rowb = bm + wm * 64 + mf * 16 + rq * 4;
#pragma unroll
      for (int r = 0; r < 4; r++) {
        float v = acc[mf][nf][r] + bv;
        if (RELU) v = fmaxf(v, 0.0f);
        size_t off = (size_t)(rowb + r) * ldc + col;
        if (WF32) C[off] = v;
        if (WSPLIT) {
          ushort h, l; split2(v, h, l);
          Ch[off] = h; Cl[off] = l;
        }
      }
    }
  }
}

// ---------------- prep: split+transpose all weights, concat qkv bias ---------
__global__ void prep_w_kernel(const float* __restrict__ wq, const float* __restrict__ wk,
                              const float* __restrict__ wv, const float* __restrict__ bq,
                              const float* __restrict__ bk, const float* __restrict__ bv,
                              const float* __restrict__ wo, const float* __restrict__ w1,
                              const float* __restrict__ w2, const float* __restrict__ wt,
                              const float* __restrict__ msm,
                              ushort* __restrict__ qkvh, ushort* __restrict__ qkvl,
                              ushort* __restrict__ woh,  ushort* __restrict__ wol,
                              ushort* __restrict__ w1h,  ushort* __restrict__ w1l,
                              ushort* __restrict__ w2h,  ushort* __restrict__ w2l,
                              ushort* __restrict__ wth,  ushort* __restrict__ wtl,
                              ushort* __restrict__ msh,  ushort* __restrict__ msl,
                              float* __restrict__ bqkv)
{
  int idx = blockIdx.x * 256 + threadIdx.x;
  if (idx < 768)
    bqkv[idx] = idx < 256 ? bq[idx] : idx < 512 ? bk[idx - 256] : bv[idx - 512];
  float v; ushort *oh, *ol; int off;
  if (idx < 196608) {                       // WqkvT [768][256]
    int n = idx >> 8, k = idx & 255;
    v = n < 256 ? wq[k * 256 + n] : n < 512 ? wk[k * 256 + n - 256] : wv[k * 256 + n - 512];
    oh = qkvh; ol = qkvl; off = idx;
  } else if (idx < 262144) {                // woT [256][256]
    int i = idx - 196608; int n = i >> 8, k = i & 255;
    v = wo[k * 256 + n]; oh = woh; ol = wol; off = i;
  } else if (idx < 393216) {                // w1T [512][256]
    int i = idx - 262144; int n = i >> 8, k = i & 255;
    v = w1[k * 512 + n]; oh = w1h; ol = w1l; off = i;
  } else if (idx < 524288) {                // w2T [256][512]
    int i = idx - 393216; int n = i >> 9, k = i & 511;
    v = w2[k * 256 + n]; oh = w2h; ol = w2l; off = i;
  } else if (idx < 589824) {                // wtT [256][256]
    int i = idx - 524288; int n = i >> 8, k = i & 255;
    v = wt[k * 256 + n]; oh = wth; ol = wtl; off = i;
  } else if (idx < 655360) {                // msymT [256][256]
    int i = idx - 589824; int n = i >> 8, k = i & 255;
    v = 0.5f * (msm[k * 256 + n] + msm[n * 256 + k]); oh = msh; ol = msl; off = i;
  } else return;
  ushort h, l; split2(v, h, l);
  oh[off] = h; ol[off] = l;
}

// ---------------- split features fp32 -> (h,l) bf16 --------------------------
__global__ void split_f_kernel(const float* __restrict__ f1, const float* __restrict__ f2,
                               ushort* __restrict__ Fh, ushort* __restrict__ Fl)
{
  int idx = (blockIdx.x * 256 + threadIdx.x) * 4;   // 3,276,800 total elems
  const float* src = idx < kR * 256 ? f1 + idx : f2 + (idx - kR * 256);
  float4 v = *(const float4*)src;
  ushort h, l;
  split2(v.x, h, l); Fh[idx + 0] = h; Fl[idx + 0] = l;
  split2(v.y, h, l); Fh[idx + 1] = h; Fl[idx + 1] = l;
  split2(v.z, h, l); Fh[idx + 2] = h; Fl[idx + 2] = l;
  split2(v.w, h, l); Fh[idx + 3] = h; Fl[idx + 3] = l;
}

// ---------------- cross-attention core (fp32), writes split bf16 -------------
__global__ __launch_bounds__(256)
void ca_attn_kernel(const float* __restrict__ P, ushort* __restrict__ Ah,
                    ushort* __restrict__ Al)
{
  const int rib  = threadIdx.x >> 6;
  const int row  = blockIdx.x * 4 + rib;
  const int lane = threadIdx.x & 63;
  const int partner = (row < kR) ? row + kR : row - kR;
  const float* q = P + (size_t)row * 768;
  const float* k = P + (size_t)partner * 768 + 256;
  const float* v = P + (size_t)partner * 768 + 512;
  const int h = lane >> 3, g = lane & 7;

  float s = 0.0f;
#pragma unroll
  for (int i = 0; i < 8; i++) {
    float4 qa = *(const float4*)(q + h * 32 + i * 4);
    float4 ka = *(const float4*)(k + g * 32 + i * 4);
    s = fmaf(qa.x, ka.x, s); s = fmaf(qa.y, ka.y, s);
    s = fmaf(qa.z, ka.z, s); s = fmaf(qa.w, ka.w, s);
  }
  s *= 0.17677669529663687f;  // 1/sqrt(32)

  float mx = s;
#pragma unroll
  for (int d = 1; d < 8; d <<= 1) mx = fmaxf(mx, __shfl_xor(mx, d));
  float e = expf(s - mx);
  float se = e;
#pragma unroll
  for (int d = 1; d < 8; d <<= 1) se += __shfl_xor(se, d);
  float w = e / se;

  __shared__ float lds_w[4][64];
  lds_w[rib][lane] = w;
  __syncthreads();

  const int dc = lane & 7;
  float o[4] = {};
#pragma unroll
  for (int gg = 0; gg < 8; gg++) {
    float wg = lds_w[rib][h * 8 + gg];
    float4 va = *(const float4*)(v + gg * 32 + dc * 4);
    o[0] = fmaf(wg, va.x, o[0]); o[1] = fmaf(wg, va.y, o[1]);
    o[2] = fmaf(wg, va.z, o[2]); o[3] = fmaf(wg, va.w, o[3]);
  }
  size_t base = (size_t)row * 256 + h * 32 + dc * 4;
#pragma unroll
  for (int j = 0; j < 4; j++) {
    ushort hh, ll; split2(o[j], hh, ll);
    Ah[base + j] = hh; Al[base + j] = ll;
  }
}

// ---------------- residual + LayerNorm, writes optional fp32 + split ---------
template<bool WF32>
__global__ __launch_bounds__(256)
void ln_res_kernel(const float* __restrict__ Y, const float* __restrict__ R1,
                   const float* __restrict__ R2, const float* __restrict__ g,
                   const float* __restrict__ b, float* __restrict__ X,
                   ushort* __restrict__ Xh, ushort* __restrict__ Xl)
{
  const int row  = blockIdx.x * 4 + (threadIdx.x >> 6);
  const int lane = threadIdx.x & 63;
  const float* res = (row < kR) ? (R1 + (size_t)row * 256)
                                : (R2 + (size_t)(row - kR) * 256);
  float4 y4 = *(const float4*)(Y + (size_t)row * 256 + lane * 4);
  float4 r4 = *(const float4*)(res + lane * 4);
  float v[4] = {y4.x + r4.x, y4.y + r4.y, y4.z + r4.z, y4.w + r4.w};

  float ssum = v[0] + v[1] + v[2] + v[3];
#pragma unroll
  for (int d = 1; d < 64; d <<= 1) ssum += __shfl_xor(ssum, d);
  float mu = ssum * (1.0f / 256.0f);
  float qq = 0.0f;
#pragma unroll
  for (int j = 0; j < 4; j++) { float dv = v[j] - mu; qq = fmaf(dv, dv, qq); }
#pragma unroll
  for (int d = 1; d < 64; d <<= 1) qq += __shfl_xor(qq, d);
  float rstd = rsqrtf(qq * (1.0f / 256.0f) + 1e-5f);

  float4 g4 = *(const float4*)(g + lane * 4);
  float4 b4 = *(const float4*)(b + lane * 4);
  float o[4];
  o[0] = (v[0] - mu) * rstd * g4.x + b4.x;
  o[1] = (v[1] - mu) * rstd * g4.y + b4.y;
  o[2] = (v[2] - mu) * rstd * g4.z + b4.z;
  o[3] = (v[3] - mu) * rstd * g4.w + b4.w;
  size_t base = (size_t)row * 256 + lane * 4;
  if (WF32) *(float4*)(X + base) = *(float4*)o;
#pragma unroll
  for (int j = 0; j < 4; j++) {
    ushort hh, ll; split2(o[j], hh, ll);
    Xh[base + j] = hh; Xl[base + j] = ll;
  }
}

// ---------------- qdot --------------------------------------------------------
__global__ __launch_bounds__(256)
void qdot_kernel(const float* __restrict__ T, const float* __restrict__ TM,
                 float* __restrict__ QD)
{
  const int row  = blockIdx.x * 4 + (threadIdx.x >> 6);
  const int lane = threadIdx.x & 63;
  float4 a = *(const float4*)(T  + (size_t)row * 256 + lane * 4);
  float4 b = *(const float4*)(TM + (size_t)row * 256 + lane * 4);
  float s = a.x * b.x + a.y * b.y + a.z * b.z + a.w * b.w;
#pragma unroll
  for (int d = 1; d < 64; d <<= 1) s += __shfl_xor(s, d);
  if (lane == 0) QD[row] = s;
}

// ---------------- cross partials ---------------------------------------------
__global__ __launch_bounds__(256)
void cross_kernel(const float* __restrict__ T1M, const float* __restrict__ T2,
                  float* __restrict__ CP)
{
  const int b  = blockIdx.x >> 1;
  const int kh = blockIdx.x & 1;
  __shared__ float sA[128][64];
  __shared__ float sB[128][64];
  const int tid = threadIdx.x;
#pragma unroll
  for (int i = 0; i < 8; i++) {
    int slot = tid + i * 256;
    int n  = slot >> 5;
    int k4 = (slot & 31) * 4;
    float4 a = make_float4(0.f, 0.f, 0.f, 0.f), c = a;
    if (n < 50) {
      a = *(const float4*)(T1M + ((size_t)b * 50 + n) * 256 + kh * 128 + k4);
      c = *(const float4*)(T2  + ((size_t)kR + b * 50 + n) * 256 + kh * 128 + k4);
    }
    sA[k4 + 0][n] = a.x; sA[k4 + 1][n] = a.y; sA[k4 + 2][n] = a.z; sA[k4 + 3][n] = a.w;
    sB[k4 + 0][n] = c.x; sB[k4 + 1][n] = c.y; sB[k4 + 2][n] = c.z; sB[k4 + 3][n] = c.w;
  }
  __syncthreads();
  const int tn = tid & 15, tm = tid >> 4;
  const int n0 = tn * 4, m0 = tm * 4;
  float acc[4][4] = {};
  for (int k = 0; k < 128; k++) {
    float4 a4 = *(const float4*)(&sA[k][n0]);
    float4 b4 = *(const float4*)(&sB[k][m0]);
    float a[4] = {a4.x, a4.y, a4.z, a4.w};
    float c[4] = {b4.x, b4.y, b4.z, b4.w};
#pragma unroll
    for (int i = 0; i < 4; i++)
#pragma unroll
      for (int j = 0; j < 4; j++)
        acc[i][j] = fmaf(a[i], c[j], acc[i][j]);
  }
#pragma unroll
  for (int i = 0; i < 4; i++) {
    float* cp = CP + (((size_t)b * 2 + kh) * 64 + n0 + i) * 64 + m0;
    *(float4*)cp = *(float4*)(&acc[i][0]);
  }
}

// ---------------- sim ---------------------------------------------------------
__global__ void sim_kernel(const float* __restrict__ CP, const float* __restrict__ QD,
                           float* __restrict__ SIM)
{
  int idx = blockIdx.x * 256 + threadIdx.x;
  if (idx >= kB * kS) return;
  int b = idx / kS, s = idx % kS;
  int n = s / kN, m = s % kN;
  float c = CP[(((size_t)b * 2 + 0) * 64 + n) * 64 + m]
          + CP[(((size_t)b * 2 + 1) * 64 + n) * 64 + m];
  float dist = QD[b * kN + n] + QD[kR + b * kN + m] - 2.0f * c;
  float z = -dist;
  z = fminf(fmaxf(z, -10.0f), 10.0f);
  SIM[idx] = expf(z);
}

// ---------------- ap attention ------------------------------------------------
__global__ __launch_bounds__(256)
void ap_kernel(const float* __restrict__ SIM, const float* __restrict__ pos,
               const float* __restrict__ wq, const float* __restrict__ bq,
               const float* __restrict__ wk, const float* __restrict__ bk,
               const float* __restrict__ wv, const float* __restrict__ bv,
               float* __restrict__ PP)
{
  const int b  = blockIdx.x / kChunks;
  const int ch = blockIdx.x % kChunks;
  const int sl = threadIdx.x >> 3;
  const int h  = threadIdx.x & 7;
  const int s  = ch * 32 + sl;
  const bool valid = (s < kS);

  __shared__ float sk[32][64];
  __shared__ float sv[32][64];
  __shared__ float satt[32][64];

  float f = valid ? SIM[(size_t)b * kS + s] : 0.0f;
  const float* pp = pos + (valid ? (size_t)s * 64 : 0) + h * 8;

  float qv[8];
#pragma unroll
  for (int d = 0; d < 8; d++) {
    int c = h * 8 + d;
    float pd = pp[d];
    qv[d] = fmaf(f, wq[c], bq[c] + pd);
    sk[sl][c] = fmaf(f, wk[c], bk[c] + pd);
    sv[sl][c] = fmaf(f, wv[c], bv[c]);
  }
  __syncthreads();

  float sc[8];
#pragma unroll
  for (int g = 0; g < 8; g++) {
    const float* kr = &sk[sl][g * 8];
    float a = 0.0f;
#pragma unroll
    for (int d = 0; d < 8; d++) a = fmaf(qv[d], kr[d], a);
    sc[g] = a * 0.35355339059327373f;
  }
  float mx = sc[0];
#pragma unroll
  for (int g = 1; g < 8; g++) mx = fmaxf(mx, sc[g]);
  float se = 0.0f;
#pragma unroll
  for (int g = 0; g < 8; g++) { sc[g] = expf(sc[g] - mx); se += sc[g]; }
  float inv = 1.0f / se;

  float av[8] = {};
#pragma unroll
  for (int g = 0; g < 8; g++) {
    float wg = sc[g] * inv;
    const float* vr = &sv[sl][g * 8];
#pragma unroll
    for (int d = 0; d < 8; d++) av[d] = fmaf(wg, vr[d], av[d]);
  }
  if (!valid) {
#pragma unroll
    for (int d = 0; d < 8; d++) av[d] = 0.0f;
  }
#pragma unroll
  for (int d = 0; d < 8; d++) satt[sl][h * 8 + d] = av[d];
  __syncthreads();

  for (int st = 16; st >= 1; st >>= 1) {
    if (sl < st) {
#pragma unroll
      for (int d = 0; d < 8; d++)
        satt[sl][h * 8 + d] += satt[sl + st][h * 8 + d];
    }
    __syncthreads();
  }
  if (sl == 0) {
#pragma unroll
    for (int d = 0; d < 8; d++)
      PP[((size_t)b * kChunks + ch) * 64 + h * 8 + d] = satt[0][h * 8 + d];
  }
}

// ---------------- final -------------------------------------------------------
__global__ __launch_bounds__(64)
void final_kernel(const float* __restrict__ PP, const float* __restrict__ wo,
                  const float* __restrict__ bo, const float* __restrict__ lg,
                  const float* __restrict__ lb, float* __restrict__ out)
{
  const int b = blockIdx.x, j = threadIdx.x;
  double acc = 0.0;
  for (int c = 0; c < kChunks; c++)
    acc += (double)PP[((size_t)b * kChunks + c) * 64 + j];
  double pooled = acc / 2500.0;
  __shared__ double sp[64];
  sp[j] = pooled;
  __syncthreads();
  double o = (double)bo[j];
  for (int d = 0; d < 64; d++) o += sp[d] * (double)wo[d * 64 + j];
  double ssum = o;
#pragma unroll
  for (int d2 = 1; d2 < 64; d2 <<= 1) ssum += __shfl_xor(ssum, d2);
  double mu = ssum / 64.0;
  double dv = o - mu;
  double qq = dv * dv;
#pragma unroll
  for (int d2 = 1; d2 < 64; d2 <<= 1) qq += __shfl_xor(qq, d2);
  double var = qq / 64.0;
  double r = 1.0 / sqrt(var + 1e-5);
  out[(size_t)b * 64 + j] = (float)(dv * r * (double)lg[j] + (double)lb[j]);
}

}  // namespace esn

extern "C" void kernel_launch(void* const* d_in, const int* in_sizes, int n_in,
                              void* d_out, int out_size, void* d_ws, size_t ws_size,
                              hipStream_t stream)
{
  using namespace esn;
  const float* f1      = (const float*)d_in[0];
  const float* f2      = (const float*)d_in[1];
  const float* ca_wq   = (const float*)d_in[2];
  const float* ca_bq   = (const float*)d_in[3];
  const float* ca_wk   = (const float*)d_in[4];
  const float* ca_bk   = (const float*)d_in[5];
  const float* ca_wv   = (const float*)d_in[6];
  const float* ca_bv   = (const float*)d_in[7];
  const float* ca_wo   = (const float*)d_in[8];
  const float* ca_bo   = (const float*)d_in[9];
  const float* ln1_g   = (const float*)d_in[10];
  const float* ln1_b   = (const float*)d_in[11];
  const float* ln2_g   = (const float*)d_in[12];
  const float* ln2_b   = (const float*)d_in[13];
  const float* ca_w1   = (const float*)d_in[14];
  const float* ca_b1   = (const float*)d_in[15];
  const float* ca_w2   = (const float*)d_in[16];
  const float* ca_b2   = (const float*)d_in[17];
  const float* ms_met  = (const float*)d_in[18];
  const float* ms_wt   = (const float*)d_in[19];
  const float* ms_bt   = (const float*)d_in[20];
  const float* ap_wq   = (const float*)d_in[21];
  const float* ap_bq   = (const float*)d_in[22];
  const float* ap_wk   = (const float*)d_in[23];
  const float* ap_bk   = (const float*)d_in[24];
  const float* ap_wv   = (const float*)d_in[25];
  const float* ap_bv   = (const float*)d_in[26];
  const float* ap_pos  = (const float*)d_in[27];
  const float* ap_wo   = (const float*)d_in[28];
  const float* ap_bo   = (const float*)d_in[29];
  const float* ap_ln_g = (const float*)d_in[30];
  const float* ap_ln_b = (const float*)d_in[31];

  float* ws = (float*)d_ws;
  // fp32 regions (offsets in floats)
  float*  P    = ws;                         // [0, 9,830,400)   12800x768
  ushort* Hh   = (ushort*)(ws);              // [0, 3,276,800)   12800x512 bf16 (after P dead)
  ushort* Hl   = (ushort*)(ws + 3276800);    // [3,276,800, 6,553,600)
  float*  TM   = ws;                         // [0, 3,276,800)   (after H dead)
  ushort* Th   = (ushort*)(ws + 3276800);    // [3,276,800, 4,915,200)
  ushort* Tl   = (ushort*)(ws + 4915200);    // [4,915,200, 6,553,600)
  float*  Tt   = ws + 6553600;               // [6,553,600, 9,830,400)
  // split-pair region (F -> ATT -> Xsplit -> Esplit), 12800x256 bf16 each
  ushort* S1h  = (ushort*)(ws + 9830400);    // [9,830,400, 11,468,800)
  ushort* S1l  = (ushort*)(ws + 11468800);   // [11,468,800, 13,107,200)
  float*  X    = ws + 13107200;              // [13,107,200, 16,384,000)
  float*  Y    = ws + 16384000;              // [16,384,000, 19,660,800)
  float*  CP   = ws + 16384000;              // overlays Y (Y dead before cross)
  float*  SIM  = ws + 17432576;              // 320,000
  float*  PP   = ws + 17752576;              // 647,168 (ends 18,399,744)
  float*  QD   = ws + 19660800;              // 12,800
  // weights (split + transposed), bf16
  ushort* Wqh  = (ushort*)(ws + 19673600);   // 196,608 bf16 = 98,304 floats
  ushort* Wql  = (ushort*)(ws + 19771904);
  ushort* Woh  = (ushort*)(ws + 19870208);   // 65,536 bf16 = 32,768 floats
  ushort* Wol  = (ushort*)(ws + 19902976);
  ushort* W1h  = (ushort*)(ws + 19935744);   // 131,072 bf16 = 65,536 floats
  ushort* W1l  = (ushort*)(ws + 20001280);
  ushort* W2h  = (ushort*)(ws + 20066816);
  ushort* W2l  = (ushort*)(ws + 20132352);
  ushort* Wth  = (ushort*)(ws + 20197888);
  ushort* Wtl  = (ushort*)(ws + 20230656);
  ushort* Msh  = (ushort*)(ws + 20263424);
  ushort* Msl  = (ushort*)(ws + 20296192);
  float*  BQKV = ws + 20328960;              // 768 (ends 20,329,728 fl = 81.3 MB)

  // 0) prep weights + split features
  prep_w_kernel<<<2560, 256, 0, stream>>>(ca_wq, ca_wk, ca_wv, ca_bq, ca_bk, ca_bv,
                                          ca_wo, ca_w1, ca_w2, ms_wt, ms_met,
                                          Wqh, Wql, Woh, Wol, W1h, W1l, W2h, W2l,
                                          Wth, Wtl, Msh, Msl, BQKV);
  split_f_kernel<<<3200, 256, 0, stream>>>(f1, f2, S1h, S1l);
  // 1) QKV: P = F @ Wqkv + b   [12800x768]
  gemm_mfma_kernel<false, true, false><<<dim3(100, 6), 256, 0, stream>>>(
      S1h, S1l, 256, Wqh, Wql, 256, BQKV, P, 768, nullptr, nullptr, 256);
  // 2) head-mixing cross-attention -> ATT split (into S1)
  ca_attn_kernel<<<kR2 / 4, 256, 0, stream>>>(P, S1h, S1l);
  // 3) o-proj: Y = ATT @ wo + bo
  gemm_mfma_kernel<false, true, false><<<dim3(100, 2), 256, 0, stream>>>(
      S1h, S1l, 256, Woh, Wol, 256, ca_bo, Y, 256, nullptr, nullptr, 256);
  // 4) LN1 -> X fp32 + Xsplit (into S1)
  ln_res_kernel<true><<<kR2 / 4, 256, 0, stream>>>(Y, f1, f2, ln1_g, ln1_b, X, S1h, S1l);
  // 5) FFN1 (relu) -> H split
  gemm_mfma_kernel<true, false, true><<<dim3(100, 4), 256, 0, stream>>>(
      S1h, S1l, 256, W1h, W1l, 256, ca_b1, nullptr, 512, Hh, Hl, 256);
  // 6) FFN2 -> Y
  gemm_mfma_kernel<false, true, false><<<dim3(100, 2), 256, 0, stream>>>(
      Hh, Hl, 512, W2h, W2l, 512, ca_b2, Y, 256, nullptr, nullptr, 512);
  // 7) LN2 -> Esplit (into S1)
  ln_res_kernel<false><<<kR2 / 4, 256, 0, stream>>>(Y, X, X + (size_t)kR * 256,
                                                    ln2_g, ln2_b, nullptr, S1h, S1l);
  // 8) t = E @ wt + bt  (fp32 + split)
  gemm_mfma_kernel<false, true, true><<<dim3(100, 2), 256, 0, stream>>>(
      S1h, S1l, 256, Wth, Wtl, 256, ms_bt, Tt, 256, Th, Tl, 256);
  // 9) tM = t @ Msym  (fp32)
  gemm_mfma_kernel<false, true, false><<<dim3(100, 2), 256, 0, stream>>>(
      Th, Tl, 256, Msh, Msl, 256, nullptr, TM, 256, nullptr, nullptr, 256);
  // 10) qdot, cross, sim
  qdot_kernel<<<kR2 / 4, 256, 0, stream>>>(Tt, TM, QD);
  cross_kernel<<<kB * 2, 256, 0, stream>>>(TM, Tt, CP);
  sim_kernel<<<(kB * kS + 255) / 256, 256, 0, stream>>>(CP, QD, SIM);
  // 11) ap attention partial pools + final
  ap_kernel<<<kB * kChunks, 256, 0, stream>>>(SIM, ap_pos, ap_wq, ap_bq, ap_wk, ap_bk,
                                              ap_wv, ap_bv, PP);
  final_kernel<<<kB, 64, 0, stream>>>(PP, ap_wo, ap_bo, ap_ln_g, ap_ln_b, (float*)d_out);
}

// Round 4
// 253.545 us; speedup vs baseline: 1.8133x; 1.0216x over previous
//
#include <hip/hip_runtime.h>
#include <cstddef>
#include <cstdint>

// ---------------------------------------------------------------------------
// EdgeSparkNet round 4: ap attention restructured via rank-1 factorization:
//   score[h,g] = (f^2*A2[h,g] + f*t1[s,h,g] + t0[s,h,g]) / sqrt(8)
//   pooled-sum = G1[h,g] @ wv + G0[h,g] @ bv,  G1=sum_s w*f, G0=sum_s w
// Lane = (h,g); per (b,s): 2 fma + 3-shfl softmax + 1 exp. Zero LDS hot loop.
// GEMM/LN/cross/sim pipeline unchanged from round 3.
// ---------------------------------------------------------------------------

namespace esn {

constexpr int kB   = 128;
constexpr int kN   = 50;
constexpr int kR   = kB * kN;      // 6400 rows per set
constexpr int kR2  = 2 * kR;       // 12800
constexpr int kS   = kN * kN;      // 2500

typedef __attribute__((ext_vector_type(8))) short short8;
typedef __attribute__((ext_vector_type(4))) float f32x4;

__device__ inline ushort f2bf_rn(float v) {
  uint32_t u = __float_as_uint(v);
  uint32_t r = (u + 0x7fffu + ((u >> 16) & 1u)) >> 16;  // round-nearest-even
  return (ushort)r;
}
__device__ inline float bf2f(ushort b) {
  return __uint_as_float(((uint32_t)b) << 16);
}
__device__ inline void split2(float v, ushort& h, ushort& l) {
  h = f2bf_rn(v);
  l = f2bf_rn(v - bf2f(h));
}

// async global->LDS, 16B per lane; LDS dest = wave-uniform base + lane*16
__device__ __forceinline__ void gld16(const ushort* g, ushort* l) {
  __builtin_amdgcn_global_load_lds(
      (const __attribute__((address_space(1))) void*)g,
      (__attribute__((address_space(3))) void*)l,
      16, 0, 0);
}

// ---------------- bf16x3 MFMA GEMM (unchanged from round 3) ------------------
template<bool RELU, bool WF32, bool WSPLIT>
__global__ __launch_bounds__(256)
void gemm_mfma_kernel(const ushort* __restrict__ Ah, const ushort* __restrict__ Al, int lda,
                      const ushort* __restrict__ Bh, const ushort* __restrict__ Bl, int ldb,
                      const float* __restrict__ bias,
                      float* __restrict__ C, int ldc,
                      ushort* __restrict__ Ch, ushort* __restrict__ Cl,
                      int K)
{
  __shared__ __align__(16) ushort sAh[128 * 32];
  __shared__ __align__(16) ushort sAl[128 * 32];
  __shared__ __align__(16) ushort sBh[128 * 32];
  __shared__ __align__(16) ushort sBl[128 * 32];

  const int tid  = threadIdx.x;
  const int lane = tid & 63;
  const int wave = tid >> 6;
  const int wm   = wave >> 1, wn = wave & 1;
  const int bm   = blockIdx.x * 128, bn = blockIdx.y * 128;

  const int lrow  = lane >> 2;
  const int lslot = lane & 3;

  f32x4 acc[4][4] = {};

  const int nK = K >> 5;
  for (int kt = 0; kt < nK; kt++) {
    const int kk = kt << 5;
#pragma unroll
    for (int i = 0; i < 2; i++) {
      const int grp  = wave * 32 + i * 16;
      const int row  = grp + lrow;
      const int c    = lslot ^ ((row >> 1) & 3);
      const size_t aoff = (size_t)(bm + row) * lda + kk + c * 8;
      const size_t boff = (size_t)(bn + row) * ldb + kk + c * 8;
      gld16(Ah + aoff, sAh + grp * 32);
      gld16(Al + aoff, sAl + grp * 32);
      gld16(Bh + boff, sBh + grp * 32);
      gld16(Bl + boff, sBl + grp * 32);
    }
    __syncthreads();

    const int r16 = lane & 15, kq = lane >> 4;
    short8 afh[4], afl[4], bfh[4], bfl[4];
#pragma unroll
    for (int f = 0; f < 4; f++) {
      int arow = wm * 64 + f * 16 + r16;
      int sa = kq ^ ((arow >> 1) & 3);
      afh[f] = *(const short8*)(sAh + arow * 32 + sa * 8);
      afl[f] = *(const short8*)(sAl + arow * 32 + sa * 8);
      int brow = wn * 64 + f * 16 + r16;
      int sb = kq ^ ((brow >> 1) & 3);
      bfh[f] = *(const short8*)(sBh + brow * 32 + sb * 8);
      bfl[f] = *(const short8*)(sBl + brow * 32 + sb * 8);
    }
#pragma unroll
    for (int mf = 0; mf < 4; mf++)
#pragma unroll
      for (int nf = 0; nf < 4; nf++) {
        acc[mf][nf] = __builtin_amdgcn_mfma_f32_16x16x32_bf16(afh[mf], bfh[nf], acc[mf][nf], 0, 0, 0);
        acc[mf][nf] = __builtin_amdgcn_mfma_f32_16x16x32_bf16(afh[mf], bfl[nf], acc[mf][nf], 0, 0, 0);
        acc[mf][nf] = __builtin_amdgcn_mfma_f32_16x16x32_bf16(afl[mf], bfh[nf], acc[mf][nf], 0, 0, 0);
      }
    __syncthreads();
  }

  const int r16 = lane & 15, rq = lane >> 4;
#pragma unroll
  for (int nf = 0; nf < 4; nf++) {
    int col = bn + wn * 64 + nf * 16 + r16;
    float bv = bias ? bias[col] : 0.0f;
#pragma unroll
    for (int mf = 0; mf < 4; mf++) {
      int rowb = bm + wm * 64 + mf * 16 + rq * 4;
#pragma unroll
      for (int r = 0; r < 4; r++) {
        float v = acc[mf][nf][r] + bv;
        if (RELU) v = fmaxf(v, 0.0f);
        size_t off = (size_t)(rowb + r) * ldc + col;
        if (WF32) C[off] = v;
        if (WSPLIT) {
          ushort h, l; split2(v, h, l);
          Ch[off] = h; Cl[off] = l;
        }
      }
    }
  }
}

// ---------------- prep: split+transpose all weights, concat qkv bias ---------
__global__ void prep_w_kernel(const float* __restrict__ wq, const float* __restrict__ wk,
                              const float* __restrict__ wv, const float* __restrict__ bq,
                              const float* __restrict__ bk, const float* __restrict__ bv,
                              const float* __restrict__ wo, const float* __restrict__ w1,
                              const float* __restrict__ w2, const float* __restrict__ wt,
                              const float* __restrict__ msm,
                              ushort* __restrict__ qkvh, ushort* __restrict__ qkvl,
                              ushort* __restrict__ woh,  ushort* __restrict__ wol,
                              ushort* __restrict__ w1h,  ushort* __restrict__ w1l,
                              ushort* __restrict__ w2h,  ushort* __restrict__ w2l,
                              ushort* __restrict__ wth,  ushort* __restrict__ wtl,
                              ushort* __restrict__ msh,  ushort* __restrict__ msl,
                              float* __restrict__ bqkv)
{
  int idx = blockIdx.x * 256 + threadIdx.x;
  if (idx < 768)
    bqkv[idx] = idx < 256 ? bq[idx] : idx < 512 ? bk[idx - 256] : bv[idx - 512];
  float v; ushort *oh, *ol; int off;
  if (idx < 196608) {                       // WqkvT [768][256]
    int n = idx >> 8, k = idx & 255;
    v = n < 256 ? wq[k * 256 + n] : n < 512 ? wk[k * 256 + n - 256] : wv[k * 256 + n - 512];
    oh = qkvh; ol = qkvl; off = idx;
  } else if (idx < 262144) {                // woT [256][256]
    int i = idx - 196608; int n = i >> 8, k = i & 255;
    v = wo[k * 256 + n]; oh = woh; ol = wol; off = i;
  } else if (idx < 393216) {                // w1T [512][256]
    int i = idx - 262144; int n = i >> 8, k = i & 255;
    v = w1[k * 512 + n]; oh = w1h; ol = w1l; off = i;
  } else if (idx < 524288) {                // w2T [256][512]
    int i = idx - 393216; int n = i >> 9, k = i & 511;
    v = w2[k * 256 + n]; oh = w2h; ol = w2l; off = i;
  } else if (idx < 589824) {                // wtT [256][256]
    int i = idx - 524288; int n = i >> 8, k = i & 255;
    v = wt[k * 256 + n]; oh = wth; ol = wtl; off = i;
  } else if (idx < 655360) {                // msymT [256][256]
    int i = idx - 589824; int n = i >> 8, k = i & 255;
    v = 0.5f * (msm[k * 256 + n] + msm[n * 256 + k]); oh = msh; ol = msl; off = i;
  } else return;
  ushort h, l; split2(v, h, l);
  oh[off] = h; ol[off] = l;
}

// ---------------- split features fp32 -> (h,l) bf16 --------------------------
__global__ void split_f_kernel(const float* __restrict__ f1, const float* __restrict__ f2,
                               ushort* __restrict__ Fh, ushort* __restrict__ Fl)
{
  int idx = (blockIdx.x * 256 + threadIdx.x) * 4;
  const float* src = idx < kR * 256 ? f1 + idx : f2 + (idx - kR * 256);
  float4 v = *(const float4*)src;
  ushort h, l;
  split2(v.x, h, l); Fh[idx + 0] = h; Fl[idx + 0] = l;
  split2(v.y, h, l); Fh[idx + 1] = h; Fl[idx + 1] = l;
  split2(v.z, h, l); Fh[idx + 2] = h; Fl[idx + 2] = l;
  split2(v.w, h, l); Fh[idx + 3] = h; Fl[idx + 3] = l;
}

// ---------------- cross-attention core (fp32), writes split bf16 -------------
__global__ __launch_bounds__(256)
void ca_attn_kernel(const float* __restrict__ P, ushort* __restrict__ Ah,
                    ushort* __restrict__ Al)
{
  const int rib  = threadIdx.x >> 6;
  const int row  = blockIdx.x * 4 + rib;
  const int lane = threadIdx.x & 63;
  const int partner = (row < kR) ? row + kR : row - kR;
  const float* q = P + (size_t)row * 768;
  const float* k = P + (size_t)partner * 768 + 256;
  const float* v = P + (size_t)partner * 768 + 512;
  const int h = lane >> 3, g = lane & 7;

  float s = 0.0f;
#pragma unroll
  for (int i = 0; i < 8; i++) {
    float4 qa = *(const float4*)(q + h * 32 + i * 4);
    float4 ka = *(const float4*)(k + g * 32 + i * 4);
    s = fmaf(qa.x, ka.x, s); s = fmaf(qa.y, ka.y, s);
    s = fmaf(qa.z, ka.z, s); s = fmaf(qa.w, ka.w, s);
  }
  s *= 0.17677669529663687f;  // 1/sqrt(32)

  float mx = s;
#pragma unroll
  for (int d = 1; d < 8; d <<= 1) mx = fmaxf(mx, __shfl_xor(mx, d));
  float e = expf(s - mx);
  float se = e;
#pragma unroll
  for (int d = 1; d < 8; d <<= 1) se += __shfl_xor(se, d);
  float w = e / se;

  __shared__ float lds_w[4][64];
  lds_w[rib][lane] = w;
  __syncthreads();

  const int dc = lane & 7;
  float o[4] = {};
#pragma unroll
  for (int gg = 0; gg < 8; gg++) {
    float wg = lds_w[rib][h * 8 + gg];
    float4 va = *(const float4*)(v + gg * 32 + dc * 4);
    o[0] = fmaf(wg, va.x, o[0]); o[1] = fmaf(wg, va.y, o[1]);
    o[2] = fmaf(wg, va.z, o[2]); o[3] = fmaf(wg, va.w, o[3]);
  }
  size_t base = (size_t)row * 256 + h * 32 + dc * 4;
#pragma unroll
  for (int j = 0; j < 4; j++) {
    ushort hh, ll; split2(o[j], hh, ll);
    Ah[base + j] = hh; Al[base + j] = ll;
  }
}

// ---------------- residual + LayerNorm, writes optional fp32 + split ---------
template<bool WF32>
__global__ __launch_bounds__(256)
void ln_res_kernel(const float* __restrict__ Y, const float* __restrict__ R1,
                   const float* __restrict__ R2, const float* __restrict__ g,
                   const float* __restrict__ b, float* __restrict__ X,
                   ushort* __restrict__ Xh, ushort* __restrict__ Xl)
{
  const int row  = blockIdx.x * 4 + (threadIdx.x >> 6);
  const int lane = threadIdx.x & 63;
  const float* res = (row < kR) ? (R1 + (size_t)row * 256)
                                : (R2 + (size_t)(row - kR) * 256);
  float4 y4 = *(const float4*)(Y + (size_t)row * 256 + lane * 4);
  float4 r4 = *(const float4*)(res + lane * 4);
  float v[4] = {y4.x + r4.x, y4.y + r4.y, y4.z + r4.z, y4.w + r4.w};

  float ssum = v[0] + v[1] + v[2] + v[3];
#pragma unroll
  for (int d = 1; d < 64; d <<= 1) ssum += __shfl_xor(ssum, d);
  float mu = ssum * (1.0f / 256.0f);
  float qq = 0.0f;
#pragma unroll
  for (int j = 0; j < 4; j++) { float dv = v[j] - mu; qq = fmaf(dv, dv, qq); }
#pragma unroll
  for (int d = 1; d < 64; d <<= 1) qq += __shfl_xor(qq, d);
  float rstd = rsqrtf(qq * (1.0f / 256.0f) + 1e-5f);

  float4 g4 = *(const float4*)(g + lane * 4);
  float4 b4 = *(const float4*)(b + lane * 4);
  float o[4];
  o[0] = (v[0] - mu) * rstd * g4.x + b4.x;
  o[1] = (v[1] - mu) * rstd * g4.y + b4.y;
  o[2] = (v[2] - mu) * rstd * g4.z + b4.z;
  o[3] = (v[3] - mu) * rstd * g4.w + b4.w;
  size_t base = (size_t)row * 256 + lane * 4;
  if (WF32) *(float4*)(X + base) = *(float4*)o;
#pragma unroll
  for (int j = 0; j < 4; j++) {
    ushort hh, ll; split2(o[j], hh, ll);
    Xh[base + j] = hh; Xl[base + j] = ll;
  }
}

// ---------------- qdot --------------------------------------------------------
__global__ __launch_bounds__(256)
void qdot_kernel(const float* __restrict__ T, const float* __restrict__ TM,
                 float* __restrict__ QD)
{
  const int row  = blockIdx.x * 4 + (threadIdx.x >> 6);
  const int lane = threadIdx.x & 63;
  float4 a = *(const float4*)(T  + (size_t)row * 256 + lane * 4);
  float4 b = *(const float4*)(TM + (size_t)row * 256 + lane * 4);
  float s = a.x * b.x + a.y * b.y + a.z * b.z + a.w * b.w;
#pragma unroll
  for (int d = 1; d < 64; d <<= 1) s += __shfl_xor(s, d);
  if (lane == 0) QD[row] = s;
}

// ---------------- cross partials ---------------------------------------------
__global__ __launch_bounds__(256)
void cross_kernel(const float* __restrict__ T1M, const float* __restrict__ T2,
                  float* __restrict__ CP)
{
  const int b  = blockIdx.x >> 1;
  const int kh = blockIdx.x & 1;
  __shared__ float sA[128][64];
  __shared__ float sB[128][64];
  const int tid = threadIdx.x;
#pragma unroll
  for (int i = 0; i < 8; i++) {
    int slot = tid + i * 256;
    int n  = slot >> 5;
    int k4 = (slot & 31) * 4;
    float4 a = make_float4(0.f, 0.f, 0.f, 0.f), c = a;
    if (n < 50) {
      a = *(const float4*)(T1M + ((size_t)b * 50 + n) * 256 + kh * 128 + k4);
      c = *(const float4*)(T2  + ((size_t)kR + b * 50 + n) * 256 + kh * 128 + k4);
    }
    sA[k4 + 0][n] = a.x; sA[k4 + 1][n] = a.y; sA[k4 + 2][n] = a.z; sA[k4 + 3][n] = a.w;
    sB[k4 + 0][n] = c.x; sB[k4 + 1][n] = c.y; sB[k4 + 2][n] = c.z; sB[k4 + 3][n] = c.w;
  }
  __syncthreads();
  const int tn = tid & 15, tm = tid >> 4;
  const int n0 = tn * 4, m0 = tm * 4;
  float acc[4][4] = {};
  for (int k = 0; k < 128; k++) {
    float4 a4 = *(const float4*)(&sA[k][n0]);
    float4 b4 = *(const float4*)(&sB[k][m0]);
    float a[4] = {a4.x, a4.y, a4.z, a4.w};
    float c[4] = {b4.x, b4.y, b4.z, b4.w};
#pragma unroll
    for (int i = 0; i < 4; i++)
#pragma unroll
      for (int j = 0; j < 4; j++)
        acc[i][j] = fmaf(a[i], c[j], acc[i][j]);
  }
#pragma unroll
  for (int i = 0; i < 4; i++) {
    float* cp = CP + (((size_t)b * 2 + kh) * 64 + n0 + i) * 64 + m0;
    *(float4*)cp = *(float4*)(&acc[i][0]);
  }
}

// ---------------- sim ---------------------------------------------------------
__global__ void sim_kernel(const float* __restrict__ CP, const float* __restrict__ QD,
                           float* __restrict__ SIM)
{
  int idx = blockIdx.x * 256 + threadIdx.x;
  if (idx >= kB * kS) return;
  int b = idx / kS, s = idx % kS;
  int n = s / kN, m = s % kN;
  float c = CP[(((size_t)b * 2 + 0) * 64 + n) * 64 + m]
          + CP[(((size_t)b * 2 + 1) * 64 + n) * 64 + m];
  float dist = QD[b * kN + n] + QD[kR + b * kN + m] - 2.0f * c;
  float z = -dist;
  z = fminf(fmaxf(z, -10.0f), 10.0f);
  SIM[idx] = expf(z);
}

// ---------------- ap tables: TT[s][lane] = {t1, t0} --------------------------
// score(f) = (f^2 * A2[h,g] + f * t1 + t0) / sqrt(8)
__global__ __launch_bounds__(256)
void ap_tables_kernel(const float* __restrict__ pos,
                      const float* __restrict__ wq, const float* __restrict__ bq,
                      const float* __restrict__ wk, const float* __restrict__ bk,
                      float2* __restrict__ TT)
{
  int idx = blockIdx.x * 256 + threadIdx.x;   // s*64 + lane
  if (idx >= kS * 64) return;
  int s = idx >> 6, lane = idx & 63;
  int h = lane >> 3, g = lane & 7;
  float t1 = 0.f, t0 = 0.f;
#pragma unroll
  for (int d = 0; d < 8; d++) {
    float a  = wq[h * 8 + d];
    float c  = bq[h * 8 + d] + pos[s * 64 + h * 8 + d];
    float bb = wk[g * 8 + d];
    float e  = bk[g * 8 + d] + pos[s * 64 + g * 8 + d];
    t1 = fmaf(a, e, t1);
    t1 = fmaf(c, bb, t1);
    t0 = fmaf(c, e, t0);
  }
  TT[idx] = make_float2(t1, t0);
}

// ---------------- ap main: accumulate G1=sum w*f, G0=sum w -------------------
// grid (128 b, 8 sb); block 256 = 4 waves; wave covers strip = sb*4+wave (79 s).
// lane = h*8+g. Writes GP[b][strip][{G1,G0}][64].
__global__ __launch_bounds__(256)
void ap_kernel(const float* __restrict__ SIM, const float2* __restrict__ TT,
               const float* __restrict__ wq, const float* __restrict__ wk,
               float* __restrict__ GP)
{
  const int b    = blockIdx.x;
  const int sb   = blockIdx.y;
  const int wave = threadIdx.x >> 6, lane = threadIdx.x & 63;
  const int strip = sb * 4 + wave;
  const int h = lane >> 3, g = lane & 7;

  float A2 = 0.f;
#pragma unroll
  for (int d = 0; d < 8; d++) A2 = fmaf(wq[h * 8 + d], wk[g * 8 + d], A2);
  const float inv8 = 0.35355339059327373f;  // 1/sqrt(8)

  float G0 = 0.f, G1 = 0.f;
  const int s0 = strip * 79;
  const int s1 = (s0 + 79 < kS) ? s0 + 79 : kS;
  for (int s = s0; s < s1; s++) {
    float f = SIM[(size_t)b * kS + s];
    float2 t = TT[s * 64 + lane];
    float x = fmaf(f * f, A2, fmaf(f, t.x, t.y)) * inv8;
    float mx = x;
    mx = fmaxf(mx, __shfl_xor(mx, 1));
    mx = fmaxf(mx, __shfl_xor(mx, 2));
    mx = fmaxf(mx, __shfl_xor(mx, 4));
    float e = __expf(x - mx);
    float se = e;
    se += __shfl_xor(se, 1);
    se += __shfl_xor(se, 2);
    se += __shfl_xor(se, 4);
    float w = e / se;
    G0 += w;
    G1 = fmaf(w, f, G1);
  }
  float* gp = GP + (((size_t)b * 32 + strip) * 2) * 64;
  gp[lane]      = G1;
  gp[64 + lane] = G0;
}

// ---------------- final: G -> pooled -> @wo+bo -> LN(64) -> out --------------
__global__ __launch_bounds__(64)
void final_kernel(const float* __restrict__ GP, const float* __restrict__ wv,
                  const float* __restrict__ bv, const float* __restrict__ wo,
                  const float* __restrict__ bo, const float* __restrict__ lg,
                  const float* __restrict__ lb, float* __restrict__ out)
{
  const int b = blockIdx.x, j = threadIdx.x;
  float G1 = 0.f, G0 = 0.f;
  for (int st = 0; st < 32; st++) {
    const float* gp = GP + (((size_t)b * 32 + st) * 2) * 64;
    G1 += gp[j];
    G0 += gp[64 + j];
  }
  __shared__ float sg1[64], sg0[64];
  sg1[j] = G1; sg0[j] = G0;
  __syncthreads();
  const int h = j >> 3, d = j & 7;
  float acc = 0.f;
#pragma unroll
  for (int g = 0; g < 8; g++) {
    acc = fmaf(sg1[h * 8 + g], wv[g * 8 + d], acc);
    acc = fmaf(sg0[h * 8 + g], bv[g * 8 + d], acc);
  }
  double pooled = (double)acc / 2500.0;
  __shared__ double sp[64];
  sp[j] = pooled;
  __syncthreads();
  double o = (double)bo[j];
  for (int dd = 0; dd < 64; dd++) o += sp[dd] * (double)wo[dd * 64 + j];
  double ssum = o;
#pragma unroll
  for (int d2 = 1; d2 < 64; d2 <<= 1) ssum += __shfl_xor(ssum, d2);
  double mu = ssum / 64.0;
  double dv = o - mu;
  double qq = dv * dv;
#pragma unroll
  for (int d2 = 1; d2 < 64; d2 <<= 1) qq += __shfl_xor(qq, d2);
  double var = qq / 64.0;
  double r = 1.0 / sqrt(var + 1e-5);
  out[(size_t)b * 64 + j] = (float)(dv * r * (double)lg[j] + (double)lb[j]);
}

}  // namespace esn

extern "C" void kernel_launch(void* const* d_in, const int* in_sizes, int n_in,
                              void* d_out, int out_size, void* d_ws, size_t ws_size,
                              hipStream_t stream)
{
  using namespace esn;
  const float* f1      = (const float*)d_in[0];
  const float* f2      = (const float*)d_in[1];
  const float* ca_wq   = (const float*)d_in[2];
  const float* ca_bq   = (const float*)d_in[3];
  const float* ca_wk   = (const float*)d_in[4];
  const float* ca_bk   = (const float*)d_in[5];
  const float* ca_wv   = (const float*)d_in[6];
  const float* ca_bv   = (const float*)d_in[7];
  const float* ca_wo   = (const float*)d_in[8];
  const float* ca_bo   = (const float*)d_in[9];
  const float* ln1_g   = (const float*)d_in[10];
  const float* ln1_b   = (const float*)d_in[11];
  const float* ln2_g   = (const float*)d_in[12];
  const float* ln2_b   = (const float*)d_in[13];
  const float* ca_w1   = (const float*)d_in[14];
  const float* ca_b1   = (const float*)d_in[15];
  const float* ca_w2   = (const float*)d_in[16];
  const float* ca_b2   = (const float*)d_in[17];
  const float* ms_met  = (const float*)d_in[18];
  const float* ms_wt   = (const float*)d_in[19];
  const float* ms_bt   = (const float*)d_in[20];
  const float* ap_wq   = (const float*)d_in[21];
  const float* ap_bq   = (const float*)d_in[22];
  const float* ap_wk   = (const float*)d_in[23];
  const float* ap_bk   = (const float*)d_in[24];
  const float* ap_wv   = (const float*)d_in[25];
  const float* ap_bv   = (const float*)d_in[26];
  const float* ap_pos  = (const float*)d_in[27];
  const float* ap_wo   = (const float*)d_in[28];
  const float* ap_bo   = (const float*)d_in[29];
  const float* ap_ln_g = (const float*)d_in[30];
  const float* ap_ln_b = (const float*)d_in[31];

  float* ws = (float*)d_ws;
  float*  P    = ws;                         // [0, 9,830,400)   12800x768
  ushort* Hh   = (ushort*)(ws);              // reuse after P dead
  ushort* Hl   = (ushort*)(ws + 3276800);
  float*  TM   = ws;                         // reuse after H dead
  ushort* Th   = (ushort*)(ws + 3276800);
  ushort* Tl   = (ushort*)(ws + 4915200);
  float*  Tt   = ws + 6553600;
  ushort* S1h  = (ushort*)(ws + 9830400);
  ushort* S1l  = (ushort*)(ws + 11468800);
  float*  X    = ws + 13107200;
  float*  Y    = ws + 16384000;
  float*  CP   = ws + 16384000;              // overlays Y (Y dead before cross)
  float*  SIM  = ws + 17432576;              // 320,000
  float*  GP   = ws + 17752576;              // 524,288 (ends 18,276,864)
  float2* TT   = (float2*)(ws + 18399744);   // 320,000 fl (ends 18,719,744)
  float*  QD   = ws + 19660800;              // 12,800
  ushort* Wqh  = (ushort*)(ws + 19673600);
  ushort* Wql  = (ushort*)(ws + 19771904);
  ushort* Woh  = (ushort*)(ws + 19870208);
  ushort* Wol  = (ushort*)(ws + 19902976);
  ushort* W1h  = (ushort*)(ws + 19935744);
  ushort* W1l  = (ushort*)(ws + 20001280);
  ushort* W2h  = (ushort*)(ws + 20066816);
  ushort* W2l  = (ushort*)(ws + 20132352);
  ushort* Wth  = (ushort*)(ws + 20197888);
  ushort* Wtl  = (ushort*)(ws + 20230656);
  ushort* Msh  = (ushort*)(ws + 20263424);
  ushort* Msl  = (ushort*)(ws + 20296192);
  float*  BQKV = ws + 20328960;

  prep_w_kernel<<<2560, 256, 0, stream>>>(ca_wq, ca_wk, ca_wv, ca_bq, ca_bk, ca_bv,
                                          ca_wo, ca_w1, ca_w2, ms_wt, ms_met,
                                          Wqh, Wql, Woh, Wol, W1h, W1l, W2h, W2l,
                                          Wth, Wtl, Msh, Msl, BQKV);
  split_f_kernel<<<3200, 256, 0, stream>>>(f1, f2, S1h, S1l);
  ap_tables_kernel<<<625, 256, 0, stream>>>(ap_pos, ap_wq, ap_bq, ap_wk, ap_bk, TT);
  gemm_mfma_kernel<false, true, false><<<dim3(100, 6), 256, 0, stream>>>(
      S1h, S1l, 256, Wqh, Wql, 256, BQKV, P, 768, nullptr, nullptr, 256);
  ca_attn_kernel<<<kR2 / 4, 256, 0, stream>>>(P, S1h, S1l);
  gemm_mfma_kernel<false, true, false><<<dim3(100, 2), 256, 0, stream>>>(
      S1h, S1l, 256, Woh, Wol, 256, ca_bo, Y, 256, nullptr, nullptr, 256);
  ln_res_kernel<true><<<kR2 / 4, 256, 0, stream>>>(Y, f1, f2, ln1_g, ln1_b, X, S1h, S1l);
  gemm_mfma_kernel<true, false, true><<<dim3(100, 4), 256, 0, stream>>>(
      S1h, S1l, 256, W1h, W1l, 256, ca_b1, nullptr, 512, Hh, Hl, 256);
  gemm_mfma_kernel<false, true, false><<<dim3(100, 2), 256, 0, stream>>>(
      Hh, Hl, 512, W2h, W2l, 512, ca_b2, Y, 256, nullptr, nullptr, 512);
  ln_res_kernel<false><<<kR2 / 4, 256, 0, stream>>>(Y, X, X + (size_t)kR * 256,
                                                    ln2_g, ln2_b, nullptr, S1h, S1l);
  gemm_mfma_kernel<false, true, true><<<dim3(100, 2), 256, 0, stream>>>(
      S1h, S1l, 256, Wth, Wtl, 256, ms_bt, Tt, 256, Th, Tl, 256);
  gemm_mfma_kernel<false, true, false><<<dim3(100, 2), 256, 0, stream>>>(
      Th, Tl, 256, Msh, Msl, 256, nullptr, TM, 256, nullptr, nullptr, 256);
  qdot_kernel<<<kR2 / 4, 256, 0, stream>>>(Tt, TM, QD);
  cross_kernel<<<kB * 2, 256, 0, stream>>>(TM, Tt, CP);
  sim_kernel<<<(kB * kS + 255) / 256, 256, 0, stream>>>(CP, QD, SIM);
  ap_kernel<<<dim3(kB, 8), 256, 0, stream>>>(SIM, TT, ap_wq, ap_wk, GP);
  final_kernel<<<kB, 64, 0, stream>>>(GP, ap_wv, ap_bv, ap_wo, ap_bo,
                                      ap_ln_g, ap_ln_b, (float*)d_out);
}

// Round 5
// 213.093 us; speedup vs baseline: 2.1575x; 1.1898x over previous
//
#include <hip/hip_runtime.h>
#include <cstddef>
#include <cstdint>

// ---------------------------------------------------------------------------
// EdgeSparkNet round 5:
//  - ap attention: lane=(sIdx,h), softmax over g fully IN-LANE (no shuffles in
//    hot loop; 48 shuffles once per strip for the final reduction).
//  - GEMM: double-buffered LDS (64KB), stage(k+1) overlaps MFMA(k), one
//    barrier per K-step.
// Rest unchanged from round 4.
// ---------------------------------------------------------------------------

namespace esn {

constexpr int kB   = 128;
constexpr int kN   = 50;
constexpr int kR   = kB * kN;      // 6400 rows per set
constexpr int kR2  = 2 * kR;       // 12800
constexpr int kS   = kN * kN;      // 2500

typedef __attribute__((ext_vector_type(8))) short short8;
typedef __attribute__((ext_vector_type(4))) float f32x4;

__device__ inline ushort f2bf_rn(float v) {
  uint32_t u = __float_as_uint(v);
  uint32_t r = (u + 0x7fffu + ((u >> 16) & 1u)) >> 16;  // round-nearest-even
  return (ushort)r;
}
__device__ inline float bf2f(ushort b) {
  return __uint_as_float(((uint32_t)b) << 16);
}
__device__ inline void split2(float v, ushort& h, ushort& l) {
  h = f2bf_rn(v);
  l = f2bf_rn(v - bf2f(h));
}

// async global->LDS, 16B per lane; LDS dest = wave-uniform base + lane*16
__device__ __forceinline__ void gld16(const ushort* g, ushort* l) {
  __builtin_amdgcn_global_load_lds(
      (const __attribute__((address_space(1))) void*)g,
      (__attribute__((address_space(3))) void*)l,
      16, 0, 0);
}

// ---------------- bf16x3 MFMA GEMM, double-buffered LDS ----------------------
// C[M,N] = A[M,K] @ W[K,N] (+bias, relu). A: split bf16 [M][K]; B: [N][K].
// BM=BN=128, BK=32, 4 waves (2x2); LDS slots XOR-swizzled by ((row>>1)&3),
// maintained write-side by pre-swizzling the global source chunk.
template<bool RELU, bool WF32, bool WSPLIT>
__global__ __launch_bounds__(256)
void gemm_mfma_kernel(const ushort* __restrict__ Ah, const ushort* __restrict__ Al, int lda,
                      const ushort* __restrict__ Bh, const ushort* __restrict__ Bl, int ldb,
                      const float* __restrict__ bias,
                      float* __restrict__ C, int ldc,
                      ushort* __restrict__ Ch, ushort* __restrict__ Cl,
                      int K)
{
  __shared__ __align__(16) ushort sAh[2][128 * 32];
  __shared__ __align__(16) ushort sAl[2][128 * 32];
  __shared__ __align__(16) ushort sBh[2][128 * 32];
  __shared__ __align__(16) ushort sBl[2][128 * 32];

  const int tid  = threadIdx.x;
  const int lane = tid & 63;
  const int wave = tid >> 6;
  const int wm   = wave >> 1, wn = wave & 1;
  const int bm   = blockIdx.x * 128, bn = blockIdx.y * 128;

  const int lrow  = lane >> 2;
  const int lslot = lane & 3;

  f32x4 acc[4][4] = {};

  auto stage = [&](int buf, int kt) {
    const int kk = kt << 5;
#pragma unroll
    for (int i = 0; i < 2; i++) {
      const int grp  = wave * 32 + i * 16;
      const int row  = grp + lrow;
      const int c    = lslot ^ ((row >> 1) & 3);
      const size_t aoff = (size_t)(bm + row) * lda + kk + c * 8;
      const size_t boff = (size_t)(bn + row) * ldb + kk + c * 8;
      gld16(Ah + aoff, &sAh[buf][grp * 32]);
      gld16(Al + aoff, &sAl[buf][grp * 32]);
      gld16(Bh + boff, &sBh[buf][grp * 32]);
      gld16(Bl + boff, &sBl[buf][grp * 32]);
    }
  };

  const int nK = K >> 5;
  stage(0, 0);
  int cur = 0;
  for (int kt = 0; kt < nK; kt++) {
    __syncthreads();   // buf[cur] staged (vmcnt drained); prior reads of buf[cur^1] done
    if (kt + 1 < nK) stage(cur ^ 1, kt + 1);   // overlaps compute below

    const int r16 = lane & 15, kq = lane >> 4;
    short8 afh[4], afl[4], bfh[4], bfl[4];
#pragma unroll
    for (int f = 0; f < 4; f++) {
      int arow = wm * 64 + f * 16 + r16;
      int sa = kq ^ ((arow >> 1) & 3);
      afh[f] = *(const short8*)(&sAh[cur][arow * 32 + sa * 8]);
      afl[f] = *(const short8*)(&sAl[cur][arow * 32 + sa * 8]);
      int brow = wn * 64 + f * 16 + r16;
      int sb = kq ^ ((brow >> 1) & 3);
      bfh[f] = *(const short8*)(&sBh[cur][brow * 32 + sb * 8]);
      bfl[f] = *(const short8*)(&sBl[cur][brow * 32 + sb * 8]);
    }
#pragma unroll
    for (int mf = 0; mf < 4; mf++)
#pragma unroll
      for (int nf = 0; nf < 4; nf++) {
        acc[mf][nf] = __builtin_amdgcn_mfma_f32_16x16x32_bf16(afh[mf], bfh[nf], acc[mf][nf], 0, 0, 0);
        acc[mf][nf] = __builtin_amdgcn_mfma_f32_16x16x32_bf16(afh[mf], bfl[nf], acc[mf][nf], 0, 0, 0);
        acc[mf][nf] = __builtin_amdgcn_mfma_f32_16x16x32_bf16(afl[mf], bfh[nf], acc[mf][nf], 0, 0, 0);
      }
    cur ^= 1;
  }

  const int r16 = lane & 15, rq = lane >> 4;
#pragma unroll
  for (int nf = 0; nf < 4; nf++) {
    int col = bn + wn * 64 + nf * 16 + r16;
    float bv = bias ? bias[col] : 0.0f;
#pragma unroll
    for (int mf = 0; mf < 4; mf++) {
      int rowb = bm + wm * 64 + mf * 16 + rq * 4;
#pragma unroll
      for (int r = 0; r < 4; r++) {
        float v = acc[mf][nf][r] + bv;
        if (RELU) v = fmaxf(v, 0.0f);
        size_t off = (size_t)(rowb + r) * ldc + col;
        if (WF32) C[off] = v;
        if (WSPLIT) {
          ushort h, l; split2(v, h, l);
          Ch[off] = h; Cl[off] = l;
        }
      }
    }
  }
}

// ---------------- prep: split+transpose all weights, concat qkv bias ---------
__global__ void prep_w_kernel(const float* __restrict__ wq, const float* __restrict__ wk,
                              const float* __restrict__ wv, const float* __restrict__ bq,
                              const float* __restrict__ bk, const float* __restrict__ bv,
                              const float* __restrict__ wo, const float* __restrict__ w1,
                              const float* __restrict__ w2, const float* __restrict__ wt,
                              const float* __restrict__ msm,
                              ushort* __restrict__ qkvh, ushort* __restrict__ qkvl,
                              ushort* __restrict__ woh,  ushort* __restrict__ wol,
                              ushort* __restrict__ w1h,  ushort* __restrict__ w1l,
                              ushort* __restrict__ w2h,  ushort* __restrict__ w2l,
                              ushort* __restrict__ wth,  ushort* __restrict__ wtl,
                              ushort* __restrict__ msh,  ushort* __restrict__ msl,
                              float* __restrict__ bqkv)
{
  int idx = blockIdx.x * 256 + threadIdx.x;
  if (idx < 768)
    bqkv[idx] = idx < 256 ? bq[idx] : idx < 512 ? bk[idx - 256] : bv[idx - 512];
  float v; ushort *oh, *ol; int off;
  if (idx < 196608) {                       // WqkvT [768][256]
    int n = idx >> 8, k = idx & 255;
    v = n < 256 ? wq[k * 256 + n] : n < 512 ? wk[k * 256 + n - 256] : wv[k * 256 + n - 512];
    oh = qkvh; ol = qkvl; off = idx;
  } else if (idx < 262144) {                // woT [256][256]
    int i = idx - 196608; int n = i >> 8, k = i & 255;
    v = wo[k * 256 + n]; oh = woh; ol = wol; off = i;
  } else if (idx < 393216) {                // w1T [512][256]
    int i = idx - 262144; int n = i >> 8, k = i & 255;
    v = w1[k * 512 + n]; oh = w1h; ol = w1l; off = i;
  } else if (idx < 524288) {                // w2T [256][512]
    int i = idx - 393216; int n = i >> 9, k = i & 511;
    v = w2[k * 256 + n]; oh = w2h; ol = w2l; off = i;
  } else if (idx < 589824) {                // wtT [256][256]
    int i = idx - 524288; int n = i >> 8, k = i & 255;
    v = wt[k * 256 + n]; oh = wth; ol = wtl; off = i;
  } else if (idx < 655360) {                // msymT [256][256]
    int i = idx - 589824; int n = i >> 8, k = i & 255;
    v = 0.5f * (msm[k * 256 + n] + msm[n * 256 + k]); oh = msh; ol = msl; off = i;
  } else return;
  ushort h, l; split2(v, h, l);
  oh[off] = h; ol[off] = l;
}

// ---------------- split features fp32 -> (h,l) bf16 --------------------------
__global__ void split_f_kernel(const float* __restrict__ f1, const float* __restrict__ f2,
                               ushort* __restrict__ Fh, ushort* __restrict__ Fl)
{
  int idx = (blockIdx.x * 256 + threadIdx.x) * 4;
  const float* src = idx < kR * 256 ? f1 + idx : f2 + (idx - kR * 256);
  float4 v = *(const float4*)src;
  ushort h, l;
  split2(v.x, h, l); Fh[idx + 0] = h; Fl[idx + 0] = l;
  split2(v.y, h, l); Fh[idx + 1] = h; Fl[idx + 1] = l;
  split2(v.z, h, l); Fh[idx + 2] = h; Fl[idx + 2] = l;
  split2(v.w, h, l); Fh[idx + 3] = h; Fl[idx + 3] = l;
}

// ---------------- cross-attention core (fp32), writes split bf16 -------------
__global__ __launch_bounds__(256)
void ca_attn_kernel(const float* __restrict__ P, ushort* __restrict__ Ah,
                    ushort* __restrict__ Al)
{
  const int rib  = threadIdx.x >> 6;
  const int row  = blockIdx.x * 4 + rib;
  const int lane = threadIdx.x & 63;
  const int partner = (row < kR) ? row + kR : row - kR;
  const float* q = P + (size_t)row * 768;
  const float* k = P + (size_t)partner * 768 + 256;
  const float* v = P + (size_t)partner * 768 + 512;
  const int h = lane >> 3, g = lane & 7;

  float s = 0.0f;
#pragma unroll
  for (int i = 0; i < 8; i++) {
    float4 qa = *(const float4*)(q + h * 32 + i * 4);
    float4 ka = *(const float4*)(k + g * 32 + i * 4);
    s = fmaf(qa.x, ka.x, s); s = fmaf(qa.y, ka.y, s);
    s = fmaf(qa.z, ka.z, s); s = fmaf(qa.w, ka.w, s);
  }
  s *= 0.17677669529663687f;  // 1/sqrt(32)

  float mx = s;
#pragma unroll
  for (int d = 1; d < 8; d <<= 1) mx = fmaxf(mx, __shfl_xor(mx, d));
  float e = expf(s - mx);
  float se = e;
#pragma unroll
  for (int d = 1; d < 8; d <<= 1) se += __shfl_xor(se, d);
  float w = e / se;

  __shared__ float lds_w[4][64];
  lds_w[rib][lane] = w;
  __syncthreads();

  const int dc = lane & 7;
  float o[4] = {};
#pragma unroll
  for (int gg = 0; gg < 8; gg++) {
    float wg = lds_w[rib][h * 8 + gg];
    float4 va = *(const float4*)(v + gg * 32 + dc * 4);
    o[0] = fmaf(wg, va.x, o[0]); o[1] = fmaf(wg, va.y, o[1]);
    o[2] = fmaf(wg, va.z, o[2]); o[3] = fmaf(wg, va.w, o[3]);
  }
  size_t base = (size_t)row * 256 + h * 32 + dc * 4;
#pragma unroll
  for (int j = 0; j < 4; j++) {
    ushort hh, ll; split2(o[j], hh, ll);
    Ah[base + j] = hh; Al[base + j] = ll;
  }
}

// ---------------- residual + LayerNorm, writes optional fp32 + split ---------
template<bool WF32>
__global__ __launch_bounds__(256)
void ln_res_kernel(const float* __restrict__ Y, const float* __restrict__ R1,
                   const float* __restrict__ R2, const float* __restrict__ g,
                   const float* __restrict__ b, float* __restrict__ X,
                   ushort* __restrict__ Xh, ushort* __restrict__ Xl)
{
  const int row  = blockIdx.x * 4 + (threadIdx.x >> 6);
  const int lane = threadIdx.x & 63;
  const float* res = (row < kR) ? (R1 + (size_t)row * 256)
                                : (R2 + (size_t)(row - kR) * 256);
  float4 y4 = *(const float4*)(Y + (size_t)row * 256 + lane * 4);
  float4 r4 = *(const float4*)(res + lane * 4);
  float v[4] = {y4.x + r4.x, y4.y + r4.y, y4.z + r4.z, y4.w + r4.w};

  float ssum = v[0] + v[1] + v[2] + v[3];
#pragma unroll
  for (int d = 1; d < 64; d <<= 1) ssum += __shfl_xor(ssum, d);
  float mu = ssum * (1.0f / 256.0f);
  float qq = 0.0f;
#pragma unroll
  for (int j = 0; j < 4; j++) { float dv = v[j] - mu; qq = fmaf(dv, dv, qq); }
#pragma unroll
  for (int d = 1; d < 64; d <<= 1) qq += __shfl_xor(qq, d);
  float rstd = rsqrtf(qq * (1.0f / 256.0f) + 1e-5f);

  float4 g4 = *(const float4*)(g + lane * 4);
  float4 b4 = *(const float4*)(b + lane * 4);
  float o[4];
  o[0] = (v[0] - mu) * rstd * g4.x + b4.x;
  o[1] = (v[1] - mu) * rstd * g4.y + b4.y;
  o[2] = (v[2] - mu) * rstd * g4.z + b4.z;
  o[3] = (v[3] - mu) * rstd * g4.w + b4.w;
  size_t base = (size_t)row * 256 + lane * 4;
  if (WF32) *(float4*)(X + base) = *(float4*)o;
#pragma unroll
  for (int j = 0; j < 4; j++) {
    ushort hh, ll; split2(o[j], hh, ll);
    Xh[base + j] = hh; Xl[base + j] = ll;
  }
}

// ---------------- qdot --------------------------------------------------------
__global__ __launch_bounds__(256)
void qdot_kernel(const float* __restrict__ T, const float* __restrict__ TM,
                 float* __restrict__ QD)
{
  const int row  = blockIdx.x * 4 + (threadIdx.x >> 6);
  const int lane = threadIdx.x & 63;
  float4 a = *(const float4*)(T  + (size_t)row * 256 + lane * 4);
  float4 b = *(const float4*)(TM + (size_t)row * 256 + lane * 4);
  float s = a.x * b.x + a.y * b.y + a.z * b.z + a.w * b.w;
#pragma unroll
  for (int d = 1; d < 64; d <<= 1) s += __shfl_xor(s, d);
  if (lane == 0) QD[row] = s;
}

// ---------------- cross partials ---------------------------------------------
__global__ __launch_bounds__(256)
void cross_kernel(const float* __restrict__ T1M, const float* __restrict__ T2,
                  float* __restrict__ CP)
{
  const int b  = blockIdx.x >> 1;
  const int kh = blockIdx.x & 1;
  __shared__ float sA[128][64];
  __shared__ float sB[128][64];
  const int tid = threadIdx.x;
#pragma unroll
  for (int i = 0; i < 8; i++) {
    int slot = tid + i * 256;
    int n  = slot >> 5;
    int k4 = (slot & 31) * 4;
    float4 a = make_float4(0.f, 0.f, 0.f, 0.f), c = a;
    if (n < 50) {
      a = *(const float4*)(T1M + ((size_t)b * 50 + n) * 256 + kh * 128 + k4);
      c = *(const float4*)(T2  + ((size_t)kR + b * 50 + n) * 256 + kh * 128 + k4);
    }
    sA[k4 + 0][n] = a.x; sA[k4 + 1][n] = a.y; sA[k4 + 2][n] = a.z; sA[k4 + 3][n] = a.w;
    sB[k4 + 0][n] = c.x; sB[k4 + 1][n] = c.y; sB[k4 + 2][n] = c.z; sB[k4 + 3][n] = c.w;
  }
  __syncthreads();
  const int tn = tid & 15, tm = tid >> 4;
  const int n0 = tn * 4, m0 = tm * 4;
  float acc[4][4] = {};
  for (int k = 0; k < 128; k++) {
    float4 a4 = *(const float4*)(&sA[k][n0]);
    float4 b4 = *(const float4*)(&sB[k][m0]);
    float a[4] = {a4.x, a4.y, a4.z, a4.w};
    float c[4] = {b4.x, b4.y, b4.z, b4.w};
#pragma unroll
    for (int i = 0; i < 4; i++)
#pragma unroll
      for (int j = 0; j < 4; j++)
        acc[i][j] = fmaf(a[i], c[j], acc[i][j]);
  }
#pragma unroll
  for (int i = 0; i < 4; i++) {
    float* cp = CP + (((size_t)b * 2 + kh) * 64 + n0 + i) * 64 + m0;
    *(float4*)cp = *(float4*)(&acc[i][0]);
  }
}

// ---------------- sim ---------------------------------------------------------
__global__ void sim_kernel(const float* __restrict__ CP, const float* __restrict__ QD,
                           float* __restrict__ SIM)
{
  int idx = blockIdx.x * 256 + threadIdx.x;
  if (idx >= kB * kS) return;
  int b = idx / kS, s = idx % kS;
  int n = s / kN, m = s % kN;
  float c = CP[(((size_t)b * 2 + 0) * 64 + n) * 64 + m]
          + CP[(((size_t)b * 2 + 1) * 64 + n) * 64 + m];
  float dist = QD[b * kN + n] + QD[kR + b * kN + m] - 2.0f * c;
  float z = -dist;
  z = fminf(fmaxf(z, -10.0f), 10.0f);
  SIM[idx] = expf(z);
}

// ---------------- ap tables: TT[s][lane] = {t1, t0} --------------------------
__global__ __launch_bounds__(256)
void ap_tables_kernel(const float* __restrict__ pos,
                      const float* __restrict__ wq, const float* __restrict__ bq,
                      const float* __restrict__ wk, const float* __restrict__ bk,
                      float2* __restrict__ TT)
{
  int idx = blockIdx.x * 256 + threadIdx.x;   // s*64 + lane
  if (idx >= kS * 64) return;
  int s = idx >> 6, lane = idx & 63;
  int h = lane >> 3, g = lane & 7;
  float t1 = 0.f, t0 = 0.f;
#pragma unroll
  for (int d = 0; d < 8; d++) {
    float a  = wq[h * 8 + d];
    float c  = bq[h * 8 + d] + pos[s * 64 + h * 8 + d];
    float bb = wk[g * 8 + d];
    float e  = bk[g * 8 + d] + pos[s * 64 + g * 8 + d];
    t1 = fmaf(a, e, t1);
    t1 = fmaf(c, bb, t1);
    t0 = fmaf(c, e, t0);
  }
  TT[idx] = make_float2(t1, t0);
}

// ---------------- ap main: lane=(sIdx,h), in-lane softmax over g -------------
// grid (128 b, 8 sb); block 256 = 4 waves; wave strip = sb*4+wave covers 79 s
// in 10 groups of 8. G1=sum_s w*f, G0=sum_s w accumulated per (h,g) in-lane,
// reduced across sIdx at the end. Writes GP[b][strip][{G1,G0}][64].
__global__ __launch_bounds__(256)
void ap_kernel(const float* __restrict__ SIM, const float2* __restrict__ TT,
               const float* __restrict__ wq, const float* __restrict__ wk,
               float* __restrict__ GP)
{
  const int b    = blockIdx.x;
  const int sb   = blockIdx.y;
  const int wave = threadIdx.x >> 6, lane = threadIdx.x & 63;
  const int strip = sb * 4 + wave;
  const int sIdx = lane >> 3;     // s within 8-group
  const int h    = lane & 7;      // head

  float wqr[8];
#pragma unroll
  for (int d = 0; d < 8; d++) wqr[d] = wq[h * 8 + d];
  float A2[8];
#pragma unroll
  for (int g = 0; g < 8; g++) {
    float a = 0.f;
#pragma unroll
    for (int d = 0; d < 8; d++) a = fmaf(wqr[d], wk[g * 8 + d], a);
    A2[g] = a;
  }
  const float inv8 = 0.35355339059327373f;  // 1/sqrt(8)

  float G0[8] = {}, G1[8] = {};
  const int s0 = strip * 79;
  for (int it = 0; it < 10; it++) {
    int rel = it * 8 + sIdx;
    int s   = s0 + rel;
    bool valid = (rel < 79) && (s < kS);
    int sc = valid ? s : (kS - 1);
    float f = SIM[(size_t)b * kS + sc];
    const float4* tp = (const float4*)(TT + sc * 64 + h * 8);
    float4 t01 = tp[0], t23 = tp[1], t45 = tp[2], t67 = tp[3];
    float f2 = f * f;
    float x[8];
    x[0] = fmaf(f2, A2[0], fmaf(f, t01.x, t01.y)) * inv8;
    x[1] = fmaf(f2, A2[1], fmaf(f, t01.z, t01.w)) * inv8;
    x[2] = fmaf(f2, A2[2], fmaf(f, t23.x, t23.y)) * inv8;
    x[3] = fmaf(f2, A2[3], fmaf(f, t23.z, t23.w)) * inv8;
    x[4] = fmaf(f2, A2[4], fmaf(f, t45.x, t45.y)) * inv8;
    x[5] = fmaf(f2, A2[5], fmaf(f, t45.z, t45.w)) * inv8;
    x[6] = fmaf(f2, A2[6], fmaf(f, t67.x, t67.y)) * inv8;
    x[7] = fmaf(f2, A2[7], fmaf(f, t67.z, t67.w)) * inv8;
    float mx = fmaxf(fmaxf(fmaxf(x[0], x[1]), fmaxf(x[2], x[3])),
                     fmaxf(fmaxf(x[4], x[5]), fmaxf(x[6], x[7])));
    float e[8], se = 0.f;
#pragma unroll
    for (int g = 0; g < 8; g++) { e[g] = __expf(x[g] - mx); se += e[g]; }
    float inv = valid ? (1.0f / se) : 0.0f;
#pragma unroll
    for (int g = 0; g < 8; g++) {
      float w = e[g] * inv;
      G0[g] += w;
      G1[g] = fmaf(w, f, G1[g]);
    }
  }
  // reduce across sIdx (lane bits 3..5)
#pragma unroll
  for (int m = 8; m <= 32; m <<= 1) {
#pragma unroll
    for (int g = 0; g < 8; g++) {
      G0[g] += __shfl_xor(G0[g], m);
      G1[g] += __shfl_xor(G1[g], m);
    }
  }
  if (sIdx == 0) {
    float* gp = GP + (((size_t)b * 32 + strip) * 2) * 64;
#pragma unroll
    for (int g = 0; g < 8; g++) {
      gp[h * 8 + g]      = G1[g];
      gp[64 + h * 8 + g] = G0[g];
    }
  }
}

// ---------------- final: G -> pooled -> @wo+bo -> LN(64) -> out --------------
__global__ __launch_bounds__(64)
void final_kernel(const float* __restrict__ GP, const float* __restrict__ wv,
                  const float* __restrict__ bv, const float* __restrict__ wo,
                  const float* __restrict__ bo, const float* __restrict__ lg,
                  const float* __restrict__ lb, float* __restrict__ out)
{
  const int b = blockIdx.x, j = threadIdx.x;
  float G1 = 0.f, G0 = 0.f;
  for (int st = 0; st < 32; st++) {
    const float* gp = GP + (((size_t)b * 32 + st) * 2) * 64;
    G1 += gp[j];
    G0 += gp[64 + j];
  }
  __shared__ float sg1[64], sg0[64];
  sg1[j] = G1; sg0[j] = G0;
  __syncthreads();
  const int h = j >> 3, d = j & 7;
  float acc = 0.f;
#pragma unroll
  for (int g = 0; g < 8; g++) {
    acc = fmaf(sg1[h * 8 + g], wv[g * 8 + d], acc);
    acc = fmaf(sg0[h * 8 + g], bv[g * 8 + d], acc);
  }
  double pooled = (double)acc / 2500.0;
  __shared__ double sp[64];
  sp[j] = pooled;
  __syncthreads();
  double o = (double)bo[j];
  for (int dd = 0; dd < 64; dd++) o += sp[dd] * (double)wo[dd * 64 + j];
  double ssum = o;
#pragma unroll
  for (int d2 = 1; d2 < 64; d2 <<= 1) ssum += __shfl_xor(ssum, d2);
  double mu = ssum / 64.0;
  double dv = o - mu;
  double qq = dv * dv;
#pragma unroll
  for (int d2 = 1; d2 < 64; d2 <<= 1) qq += __shfl_xor(qq, d2);
  double var = qq / 64.0;
  double r = 1.0 / sqrt(var + 1e-5);
  out[(size_t)b * 64 + j] = (float)(dv * r * (double)lg[j] + (double)lb[j]);
}

}  // namespace esn

extern "C" void kernel_launch(void* const* d_in, const int* in_sizes, int n_in,
                              void* d_out, int out_size, void* d_ws, size_t ws_size,
                              hipStream_t stream)
{
  using namespace esn;
  const float* f1      = (const float*)d_in[0];
  const float* f2      = (const float*)d_in[1];
  const float* ca_wq   = (const float*)d_in[2];
  const float* ca_bq   = (const float*)d_in[3];
  const float* ca_wk   = (const float*)d_in[4];
  const float* ca_bk   = (const float*)d_in[5];
  const float* ca_wv   = (const float*)d_in[6];
  const float* ca_bv   = (const float*)d_in[7];
  const float* ca_wo   = (const float*)d_in[8];
  const float* ca_bo   = (const float*)d_in[9];
  const float* ln1_g   = (const float*)d_in[10];
  const float* ln1_b   = (const float*)d_in[11];
  const float* ln2_g   = (const float*)d_in[12];
  const float* ln2_b   = (const float*)d_in[13];
  const float* ca_w1   = (const float*)d_in[14];
  const float* ca_b1   = (const float*)d_in[15];
  const float* ca_w2   = (const float*)d_in[16];
  const float* ca_b2   = (const float*)d_in[17];
  const float* ms_met  = (const float*)d_in[18];
  const float* ms_wt   = (const float*)d_in[19];
  const float* ms_bt   = (const float*)d_in[20];
  const float* ap_wq   = (const float*)d_in[21];
  const float* ap_bq   = (const float*)d_in[22];
  const float* ap_wk   = (const float*)d_in[23];
  const float* ap_bk   = (const float*)d_in[24];
  const float* ap_wv   = (const float*)d_in[25];
  const float* ap_bv   = (const float*)d_in[26];
  const float* ap_pos  = (const float*)d_in[27];
  const float* ap_wo   = (const float*)d_in[28];
  const float* ap_bo   = (const float*)d_in[29];
  const float* ap_ln_g = (const float*)d_in[30];
  const float* ap_ln_b = (const float*)d_in[31];

  float* ws = (float*)d_ws;
  float*  P    = ws;                         // [0, 9,830,400)   12800x768
  ushort* Hh   = (ushort*)(ws);              // reuse after P dead
  ushort* Hl   = (ushort*)(ws + 3276800);
  float*  TM   = ws;                         // reuse after H dead
  ushort* Th   = (ushort*)(ws + 3276800);
  ushort* Tl   = (ushort*)(ws + 4915200);
  float*  Tt   = ws + 6553600;
  ushort* S1h  = (ushort*)(ws + 9830400);
  ushort* S1l  = (ushort*)(ws + 11468800);
  float*  X    = ws + 13107200;
  float*  Y    = ws + 16384000;
  float*  CP   = ws + 16384000;              // overlays Y (Y dead before cross)
  float*  SIM  = ws + 17432576;              // 320,000
  float*  GP   = ws + 17752576;              // 524,288 (ends 18,276,864)
  float2* TT   = (float2*)(ws + 18399744);   // 320,000 fl (ends 18,719,744)
  float*  QD   = ws + 19660800;              // 12,800
  ushort* Wqh  = (ushort*)(ws + 19673600);
  ushort* Wql  = (ushort*)(ws + 19771904);
  ushort* Woh  = (ushort*)(ws + 19870208);
  ushort* Wol  = (ushort*)(ws + 19902976);
  ushort* W1h  = (ushort*)(ws + 19935744);
  ushort* W1l  = (ushort*)(ws + 20001280);
  ushort* W2h  = (ushort*)(ws + 20066816);
  ushort* W2l  = (ushort*)(ws + 20132352);
  ushort* Wth  = (ushort*)(ws + 20197888);
  ushort* Wtl  = (ushort*)(ws + 20230656);
  ushort* Msh  = (ushort*)(ws + 20263424);
  ushort* Msl  = (ushort*)(ws + 20296192);
  float*  BQKV = ws + 20328960;

  prep_w_kernel<<<2560, 256, 0, stream>>>(ca_wq, ca_wk, ca_wv, ca_bq, ca_bk, ca_bv,
                                          ca_wo, ca_w1, ca_w2, ms_wt, ms_met,
                                          Wqh, Wql, Woh, Wol, W1h, W1l, W2h, W2l,
                                          Wth, Wtl, Msh, Msl, BQKV);
  split_f_kernel<<<3200, 256, 0, stream>>>(f1, f2, S1h, S1l);
  ap_tables_kernel<<<625, 256, 0, stream>>>(ap_pos, ap_wq, ap_bq, ap_wk, ap_bk, TT);
  gemm_mfma_kernel<false, true, false><<<dim3(100, 6), 256, 0, stream>>>(
      S1h, S1l, 256, Wqh, Wql, 256, BQKV, P, 768, nullptr, nullptr, 256);
  ca_attn_kernel<<<kR2 / 4, 256, 0, stream>>>(P, S1h, S1l);
  gemm_mfma_kernel<false, true, false><<<dim3(100, 2), 256, 0, stream>>>(
      S1h, S1l, 256, Woh, Wol, 256, ca_bo, Y, 256, nullptr, nullptr, 256);
  ln_res_kernel<true><<<kR2 / 4, 256, 0, stream>>>(Y, f1, f2, ln1_g, ln1_b, X, S1h, S1l);
  gemm_mfma_kernel<true, false, true><<<dim3(100, 4), 256, 0, stream>>>(
      S1h, S1l, 256, W1h, W1l, 256, ca_b1, nullptr, 512, Hh, Hl, 256);
  gemm_mfma_kernel<false, true, false><<<dim3(100, 2), 256, 0, stream>>>(
      Hh, Hl, 512, W2h, W2l, 512, ca_b2, Y, 256, nullptr, nullptr, 512);
  ln_res_kernel<false><<<kR2 / 4, 256, 0, stream>>>(Y, X, X + (size_t)kR * 256,
                                                    ln2_g, ln2_b, nullptr, S1h, S1l);
  gemm_mfma_kernel<false, true, true><<<dim3(100, 2), 256, 0, stream>>>(
      S1h, S1l, 256, Wth, Wtl, 256, ms_bt, Tt, 256, Th, Tl, 256);
  gemm_mfma_kernel<false, true, false><<<dim3(100, 2), 256, 0, stream>>>(
      Th, Tl, 256, Msh, Msl, 256, nullptr, TM, 256, nullptr, nullptr, 256);
  qdot_kernel<<<kR2 / 4, 256, 0, stream>>>(Tt, TM, QD);
  cross_kernel<<<kB * 2, 256, 0, stream>>>(TM, Tt, CP);
  sim_kernel<<<(kB * kS + 255) / 256, 256, 0, stream>>>(CP, QD, SIM);
  ap_kernel<<<dim3(kB, 8), 256, 0, stream>>>(SIM, TT, ap_wq, ap_wk, GP);
  final_kernel<<<kB, 64, 0, stream>>>(GP, ap_wv, ap_bv, ap_wo, ap_bo,
                                      ap_ln_g, ap_ln_b, (float*)d_out);
}